// Round 7
// baseline (723.859 us; speedup 1.0000x reference)
//
#include <hip/hip_runtime.h>
#include <hip/hip_bf16.h>
#include <math.h>

typedef __hip_bfloat16 bf16;
typedef __attribute__((ext_vector_type(8))) short short8;   // 8 x bf16 MFMA frag
typedef __attribute__((ext_vector_type(4))) float floatx4;  // 4 x f32 MFMA acc

// Problem constants: B=64, DIM=256, HID=512, NH=4, KD=16, D=64, 28x28, WH=7
#define BB    64
#define DIMC  256
#define HIDC  512
#define NHH   4
#define HH_   28
#define WW_   28
#define PP    784   // 28*28

__device__ __forceinline__ float toF(bf16 x) { return __bfloat162float(x); }
__device__ __forceinline__ unsigned short f2bits(float f) {
    union { bf16 h; unsigned short u; } cv; cv.h = __float2bfloat16(f); return cv.u;
}
__device__ __forceinline__ float bits2f(unsigned short u) {
    union { unsigned int u32; float f; } cv; cv.u32 = ((unsigned int)u) << 16; return cv.f;
}

// ---------------------------------------------------------------------------
// fp32 -> bf16 weight convert — single merged launch for all 6 weight arrays
// ---------------------------------------------------------------------------
__global__ __launch_bounds__(256) void cvt_all(
    const float* __restrict__ s0, bf16* __restrict__ d0,   // 131072
    const float* __restrict__ s1, bf16* __restrict__ d1,   // 131072
    const float* __restrict__ s2, bf16* __restrict__ d2,   // 131072
    const float* __restrict__ s3, bf16* __restrict__ d3,   // 131072
    const float* __restrict__ s4, bf16* __restrict__ d4,   // 98304
    const float* __restrict__ s5, bf16* __restrict__ d5)   // 65536
{
    int i = blockIdx.x * 256 + threadIdx.x;
    if (i < 131072)                d0[i]          = __float2bfloat16(s0[i]);
    else if (i < 262144)           d1[i - 131072] = __float2bfloat16(s1[i - 131072]);
    else if (i < 393216)           d2[i - 262144] = __float2bfloat16(s2[i - 262144]);
    else if (i < 524288)           d3[i - 393216] = __float2bfloat16(s3[i - 393216]);
    else if (i < 622592)           d4[i - 524288] = __float2bfloat16(s4[i - 524288]);
    else if (i < 688128)           d5[i - 622592] = __float2bfloat16(s5[i - 622592]);
}

// ---------------------------------------------------------------------------
// fp32 NCHW [64][256][784] -> bf16 NHWC [64][784][256] (LDS 32x32 transpose)
// grid (25, 8, 64), block 256
// ---------------------------------------------------------------------------
__global__ __launch_bounds__(256) void tr_cvt(
    const float* __restrict__ in, bf16* __restrict__ out)
{
    __shared__ float t[32][33];
    int n  = blockIdx.z;
    int p0 = blockIdx.x * 32;
    int c0 = blockIdx.y * 32;
    int tx = threadIdx.x & 31;
    int ty = threadIdx.x >> 5;   // 0..7
#pragma unroll
    for (int e = 0; e < 4; e++) {
        int c = c0 + ty + e * 8;
        int p = p0 + tx;
        if (p < PP) t[ty + e * 8][tx] = in[((size_t)n * DIMC + c) * PP + p];
    }
    __syncthreads();
#pragma unroll
    for (int e = 0; e < 4; e++) {
        int p = p0 + ty + e * 8;
        int c = c0 + tx;
        if (p < PP) out[((size_t)n * PP + p) * DIMC + c] = __float2bfloat16(t[tx][ty + e * 8]);
    }
}

// ---------------------------------------------------------------------------
// Depthwise 3x3 conv + BN + residual (NCHW fp32) — round-0 LDS version.
// ---------------------------------------------------------------------------
#define CPB 4
__global__ __launch_bounds__(256) void dw3x3_kernel(
    const float* __restrict__ in, const float* __restrict__ w,
    const float* __restrict__ s, const float* __restrict__ b,
    float* __restrict__ out)
{
    __shared__ float t[CPB][30 * 30];        // padded planes, zero halo
    __shared__ float wS[CPB * 9 + 2 * CPB];  // 9 weights + scale + bias per ch

    int n   = blockIdx.x;
    int c0  = blockIdx.y * CPB;
    int tid = threadIdx.x;
    const float* ip = in  + ((size_t)n * DIMC + c0) * PP;
    float*       op = out + ((size_t)n * DIMC + c0) * PP;

    // weights/scale/bias -> LDS
    if (tid < CPB * 9)                wS[tid] = w[c0 * 9 + tid];
    else if (tid < CPB * 10)          wS[tid] = s[c0 + tid - CPB * 9];
    else if (tid < CPB * 11)          wS[tid] = b[c0 + tid - CPB * 10];

    // zero-fill padded planes (halo must be 0; interior overwritten below)
    for (int i = tid; i < CPB * 900; i += 256) ((float*)t)[i] = 0.f;
    __syncthreads();

    // stage: CPB*196 float4 tasks; each row of 28 = 7 aligned float4
    for (int idx = tid; idx < CPB * 196; idx += 256) {
        int ch  = idx / 196;
        int rm  = idx - ch * 196;
        int row = rm / 7, seg = rm - row * 7;
        float4 v = *(const float4*)&ip[ch * PP + row * 28 + seg * 4];
        float* dst = &t[ch][(row + 1) * 30 + seg * 4 + 1];
        dst[0] = v.x; dst[1] = v.y; dst[2] = v.z; dst[3] = v.w;
    }
    __syncthreads();

    // compute: 4-px segments; padded window rows row..row+2, cols x0..x0+5
    for (int idx = tid; idx < CPB * 196; idx += 256) {
        int ch  = idx / 196;
        int rm  = idx - ch * 196;
        int row = rm / 7, seg = rm - row * 7;
        int x0  = seg * 4;
        float w9[9];
#pragma unroll
        for (int i = 0; i < 9; i++) w9[i] = wS[ch * 9 + i];
        float sc = wS[CPB * 9 + ch], bb = wS[CPB * 10 + ch];

        float acc[4] = {0.f, 0.f, 0.f, 0.f};
        float ctr[4];
        const float* base = &t[ch][row * 30 + x0];
#pragma unroll
        for (int i = 0; i < 3; i++) {
            float r[6];
#pragma unroll
            for (int k = 0; k < 6; k++) r[k] = base[i * 30 + k];
            if (i == 1) { ctr[0] = r[1]; ctr[1] = r[2]; ctr[2] = r[3]; ctr[3] = r[4]; }
#pragma unroll
            for (int j = 0; j < 3; j++)
#pragma unroll
                for (int q = 0; q < 4; q++)
                    acc[q] += w9[i * 3 + j] * r[j + q];
        }
        float4 o;
        o.x = ctr[0] + acc[0] * sc + bb;
        o.y = ctr[1] + acc[1] * sc + bb;
        o.z = ctr[2] + acc[2] * sc + bb;
        o.w = ctr[3] + acc[3] * sc + bb;
        *(float4*)&op[ch * PP + row * 28 + x0] = o;
    }
}

// ---------------------------------------------------------------------------
// Per-head depthwise 5x5 + BN on q channels — round-5 LDS version (proven).
// grid (NHH, BB), block 256, LDS 32 KB.
// ---------------------------------------------------------------------------
__global__ __launch_bounds__(256) void dws5x5_nhwc(
    const bf16* __restrict__ qkv,   // [64][784][384]
    const float* __restrict__ w,    // [64][25]  (hk-major)
    const float* __restrict__ s, const float* __restrict__ b,
    bf16* __restrict__ qout)        // [64][784][64]
{
    __shared__ __align__(16) unsigned short qin[32 * 32 * 16];  // [r][c][ch]
    int hh  = blockIdx.x;
    int n   = blockIdx.y;
    int tid = threadIdx.x;
    const unsigned short* KVu = (const unsigned short*)qkv;

    int kcw = tid & 15;
    int hk  = hh * 16 + kcw;
    float w25[25];
#pragma unroll
    for (int i = 0; i < 25; i++) w25[i] = w[hk * 25 + i];
    float csc = s[hk], cbb = b[hk];

    // zero-fill (halo must be 0), then stage interior
    for (int i = tid; i < 4096; i += 256)
        ((uint4*)qin)[i] = make_uint4(0u, 0u, 0u, 0u);
    __syncthreads();
    for (int idx = tid; idx < 1568; idx += 256) {
        int p = idx >> 1, half = idx & 1;
        int h = p / 28, x = p - h * 28;
        uint4 v = *(const uint4*)&KVu[((size_t)n * PP + p) * 384 + hh * 96 + half * 8];
        *(uint4*)&qin[((h + 2) * 32 + (x + 2)) * 16 + half * 8] = v;
    }
    __syncthreads();

    // compute: 784 px x 16 ch tasks
    for (int idx = tid; idx < 12544; idx += 256) {
        int p = idx >> 4;            // channel == kcw since 256 % 16 == 0
        int h = p / 28, x = p - h * 28;
        float acc = 0.f;
#pragma unroll
        for (int i = 0; i < 5; i++)
#pragma unroll
            for (int j = 0; j < 5; j++)
                acc += w25[i * 5 + j] * bits2f(qin[((h + i) * 32 + (x + j)) * 16 + kcw]);
        qout[((size_t)n * PP + p) * 64 + hk] = __float2bfloat16(acc * csc + cbb);
    }
}

// ---------------------------------------------------------------------------
// 1x1 conv as bf16 MFMA GEMM — round-3 2-phase double-buffered pipeline.
// Still used for qkv + proj. Tile 64(co) x 112(p), K-step 32, 4 waves.
// OUTMODE: 0 = bf16 NHWC; 1 = fp32 NCHW; 2 = both.   grid (7, M/64, 64)
// ---------------------------------------------------------------------------
template <bool RELU, bool RES, int OUTMODE>
__global__ __launch_bounds__(256) void gemm_mfma(
    const bf16* __restrict__ Wb,    // [M][K] bf16
    const bf16* __restrict__ X,     // [64][784][K] bf16 NHWC
    const float* __restrict__ S, const float* __restrict__ Bb,
    const float* __restrict__ res,  // [64][M][784] fp32 NCHW (if RES)
    float* __restrict__ outF,       // fp32 NCHW (OUTMODE 1/2)
    bf16*  __restrict__ outB,       // bf16 NHWC (OUTMODE 0/2)
    int M, int K)
{
    int n    = blockIdx.z;
    int co0  = blockIdx.y * 64;
    int p0   = blockIdx.x * 112;
    int tid  = threadIdx.x;
    int wv   = tid >> 6;
    int ln   = tid & 63;
    int l15  = ln & 15;
    int quad = ln >> 4;

    __shared__ __align__(16) unsigned short Blds[2][112 * 40];  // dbuf, pitch 40

    floatx4 acc[7];
#pragma unroll
    for (int t = 0; t < 7; t++) acc[t] = (floatx4){0.f, 0.f, 0.f, 0.f};

    const bf16* Arow = Wb + (size_t)(co0 + wv * 16 + l15) * K + quad * 8;
    const unsigned short* Xb = (const unsigned short*)X + ((size_t)n * PP + p0) * K;

    int pp_a = tid >> 2, G_a = tid & 3;                 // pp_a in [0,64)
    int idx_b = tid + 256;
    int pp_b = idx_b >> 2, G_b = idx_b & 3;             // pp_b in [64,128), valid < 112
    bool has_b = idx_b < 448;

    const unsigned short* pa = Xb + (size_t)pp_a * K + G_a * 8;
    const unsigned short* pb = Xb + (size_t)pp_b * K + G_b * 8;

    // prologue: stage tile 0 into LDS[0]; A-frag 0 into regs
    {
        uint4 va = *(const uint4*)pa;
        *(uint4*)&Blds[0][pp_a * 40 + G_a * 8] = va;
        if (has_b) {
            uint4 vb = *(const uint4*)pb;
            *(uint4*)&Blds[0][pp_b * 40 + G_b * 8] = vb;
        }
    }
    short8 af = *(const short8*)Arow;
    __syncthreads();

    int NT = K >> 5;
    for (int t = 0; t < NT; t++) {
        int cur = t & 1;
        uint4 nva = make_uint4(0u, 0u, 0u, 0u), nvb = make_uint4(0u, 0u, 0u, 0u);
        short8 naf = af;
        if (t + 1 < NT) {
            nva = *(const uint4*)(pa + (t + 1) * 32);
            if (has_b) nvb = *(const uint4*)(pb + (t + 1) * 32);
            naf = *(const short8*)(Arow + (t + 1) * 32);
        }
#pragma unroll
        for (int tt = 0; tt < 7; tt++) {
            short8 bfrag = *(const short8*)&Blds[cur][(tt * 16 + l15) * 40 + quad * 8];
            acc[tt] = __builtin_amdgcn_mfma_f32_16x16x32_bf16(af, bfrag, acc[tt], 0, 0, 0);
        }
        if (t + 1 < NT) {
            __syncthreads();
            *(uint4*)&Blds[cur ^ 1][pp_a * 40 + G_a * 8] = nva;
            if (has_b) *(uint4*)&Blds[cur ^ 1][pp_b * 40 + G_b * 8] = nvb;
            af = naf;
            __syncthreads();
        }
    }

    int cobase = co0 + wv * 16 + quad * 4;
    float s4[4], b4[4];
#pragma unroll
    for (int r = 0; r < 4; r++) { s4[r] = S[cobase + r]; b4[r] = Bb[cobase + r]; }

#pragma unroll
    for (int t = 0; t < 7; t++) {
        int p = p0 + t * 16 + l15;   // always < 784
        float y[4];
#pragma unroll
        for (int r = 0; r < 4; r++) {
            y[r] = acc[t][r] * s4[r] + b4[r];
            if (RELU) y[r] = fmaxf(y[r], 0.f);
            if (RES) y[r] += res[((size_t)n * M + cobase + r) * PP + p];
        }
        if (OUTMODE == 1 || OUTMODE == 2) {
#pragma unroll
            for (int r = 0; r < 4; r++)
                outF[((size_t)n * M + cobase + r) * PP + p] = y[r];
        }
        if (OUTMODE == 0 || OUTMODE == 2) {
            union { unsigned short h4[4]; uint2 u; } pk;
#pragma unroll
            for (int r = 0; r < 4; r++) pk.h4[r] = f2bits(y[r]);
            *(uint2*)((unsigned short*)outB + ((size_t)n * PP + p) * M + cobase) = pk.u;
        }
    }
}

// ---------------------------------------------------------------------------
// Fused FFN: out = bn2(W2 @ relu(bn1(W1 @ x))) + res — ROUND-6.
// Eliminates the 51.4 MB Hb intermediate (write+read, x2 ffns = 205.6 MB HBM).
// Block = 64-px tile x all channels. Phase 1: 8 co-passes x 8 K-steps compute
// hidden[64px][512] bf16 into LDS (exact replica of the proven GEMM loop:
// same tiling, K-order, bf16 cast -> bit-identical numerics). Phase 2: 4
// co-passes x 16 K-steps read B-frags straight from LDS hid (no barriers,
// no staging) + residual add + store.
// Safety: block reads ONLY its own 64 px rows of X and writes only those rows
// (in-place X1b refresh for OUT2MODE==2 has no cross-block hazard).
// LDS: hid [64][520] u16 (pitch 520 -> 2-way bank aliasing = free) 66560 B
//      + Xd [2][64][40] u16 dbuf 10240 B = 76800 B -> 2 blocks/CU.
// OUT2MODE: 2 = fp32 NCHW + bf16 NHWC mirror; 1 = fp32 NCHW only.
// grid (13, 64) — last px-tile masked. block 256.
// ---------------------------------------------------------------------------
template <int OUT2MODE>
__global__ __launch_bounds__(256) void ffn_fused(
    const bf16* __restrict__ W1,   // [512][256]
    const float* __restrict__ S1, const float* __restrict__ B1,
    const bf16* __restrict__ W2,   // [256][512]
    const float* __restrict__ S2, const float* __restrict__ B2,
    const bf16* __restrict__ X,    // [64][784][256] NHWC bf16
    const float* __restrict__ res, // [64][256][784] fp32 NCHW
    float* __restrict__ outF,      // [64][256][784] fp32 NCHW
    bf16*  __restrict__ outB)      // [64][784][256] bf16 NHWC (OUT2MODE==2)
{
    int n   = blockIdx.y;
    int p0  = blockIdx.x * 64;
    int tid = threadIdx.x;
    int wv  = tid >> 6, ln = tid & 63, l15 = ln & 15, quad = ln >> 4;

    __shared__ __align__(16) char smem[76800];
    unsigned short* hid = (unsigned short*)smem;             // [64][520]
    unsigned short* Xd  = (unsigned short*)(smem + 66560);   // [2][64][40]

    const unsigned short* Xu = (const unsigned short*)X;

    // staging: thread -> (lp = tid>>2, G = tid&3); exactly one uint4/step
    int lp_s = tid >> 2, G_s = tid & 3;
    int p_s  = p0 + lp_s;
    bool vs  = p_s < PP;
    const unsigned short* px_src = Xu + ((size_t)n * PP + (vs ? p_s : 0)) * DIMC + G_s * 8;

    // ---------------- phase 1: hid = relu(bn1(W1 @ x)) ----------------
    const bf16* A1base = W1 + (size_t)(wv * 16 + l15) * DIMC + quad * 8;

    {
        uint4 v = vs ? *(const uint4*)px_src : make_uint4(0u, 0u, 0u, 0u);
        *(uint4*)&Xd[lp_s * 40 + G_s * 8] = v;
    }
    short8 af = *(const short8*)A1base;   // pass 0, k0 = 0
    __syncthreads();

    floatx4 acc[4];
#pragma unroll
    for (int t = 0; t < 4; t++) acc[t] = (floatx4){0.f, 0.f, 0.f, 0.f};

    for (int g = 0; g < 64; g++) {           // g = pass*8 + s
        int s = g & 7, pass = g >> 3, cur = g & 1;
        uint4 nv = make_uint4(0u, 0u, 0u, 0u);
        short8 naf = af;
        if (g + 1 < 64) {
            int s2 = (g + 1) & 7, pz = (g + 1) >> 3;
            if (vs) nv = *(const uint4*)(px_src + s2 * 32);
            naf = *(const short8*)(A1base + (size_t)pz * 64 * DIMC + s2 * 32);
        }
#pragma unroll
        for (int t = 0; t < 4; t++) {
            short8 bfrag = *(const short8*)&Xd[cur * 2560 + (t * 16 + l15) * 40 + quad * 8];
            acc[t] = __builtin_amdgcn_mfma_f32_16x16x32_bf16(af, bfrag, acc[t], 0, 0, 0);
        }
        if (s == 7) {
            int cobase = pass * 64 + wv * 16 + quad * 4;
            float s4[4], b4[4];
#pragma unroll
            for (int r = 0; r < 4; r++) { s4[r] = S1[cobase + r]; b4[r] = B1[cobase + r]; }
#pragma unroll
            for (int t = 0; t < 4; t++) {
                union { unsigned short h[4]; uint2 u; } pk;
#pragma unroll
                for (int r = 0; r < 4; r++)
                    pk.h[r] = f2bits(fmaxf(acc[t][r] * s4[r] + b4[r], 0.f));
                *(uint2*)&hid[(t * 16 + l15) * 520 + cobase] = pk.u;
                acc[t] = (floatx4){0.f, 0.f, 0.f, 0.f};
            }
        }
        if (g + 1 < 64) {
            __syncthreads();
            *(uint4*)&Xd[(cur ^ 1) * 2560 + lp_s * 40 + G_s * 8] = nv;
            af = naf;
            __syncthreads();
        }
    }
    __syncthreads();   // hid complete; all X reads done (in-place outB safe)

    // ---------------- phase 2: out = bn2(W2 @ hid) + res ----------------
#pragma unroll 1
    for (int pass = 0; pass < 4; pass++) {
        const bf16* A2 = W2 + (size_t)(pass * 64 + wv * 16 + l15) * HIDC + quad * 8;
        floatx4 a2[4];
#pragma unroll
        for (int t = 0; t < 4; t++) a2[t] = (floatx4){0.f, 0.f, 0.f, 0.f};
        short8 af2 = *(const short8*)A2;
        for (int s = 0; s < 16; s++) {
            short8 naf2 = af2;
            if (s + 1 < 16) naf2 = *(const short8*)(A2 + (s + 1) * 32);
#pragma unroll
            for (int t = 0; t < 4; t++) {
                short8 bfrag = *(const short8*)&hid[(t * 16 + l15) * 520 + s * 32 + quad * 8];
                a2[t] = __builtin_amdgcn_mfma_f32_16x16x32_bf16(af2, bfrag, a2[t], 0, 0, 0);
            }
            af2 = naf2;
        }
        int cobase = pass * 64 + wv * 16 + quad * 4;
        float s4[4], b4[4];
#pragma unroll
        for (int r = 0; r < 4; r++) { s4[r] = S2[cobase + r]; b4[r] = B2[cobase + r]; }
#pragma unroll
        for (int t = 0; t < 4; t++) {
            int p = p0 + t * 16 + l15;
            if (p < PP) {
                float y[4];
#pragma unroll
                for (int r = 0; r < 4; r++) {
                    y[r] = a2[t][r] * s4[r] + b4[r]
                         + res[((size_t)n * DIMC + cobase + r) * PP + p];
                }
#pragma unroll
                for (int r = 0; r < 4; r++)
                    outF[((size_t)n * DIMC + cobase + r) * PP + p] = y[r];
                if (OUT2MODE == 2) {
                    union { unsigned short h4[4]; uint2 u; } pk;
#pragma unroll
                    for (int r = 0; r < 4; r++) pk.h4[r] = f2bits(y[r]);
                    *(uint2*)((unsigned short*)outB + ((size_t)n * PP + p) * DIMC + cobase) = pk.u;
                }
            }
        }
    }
}

// ---------------------------------------------------------------------------
// 7x7 window attention — round-1 MFMA version (proven).
// grid (8, 4, 64), block 256.
// ---------------------------------------------------------------------------
__global__ __launch_bounds__(256) void attn_kernel(
    const bf16*  __restrict__ Q,       // [64][784][64] NHWC (hk = hh*16+kc)
    const bf16*  __restrict__ KV,      // [64][784][384] NHWC
    const float* __restrict__ pos,     // [4][49][49]
    bf16* __restrict__ O)              // [64][784][256] NHWC (c = hh*64+d)
{
    int wjp = blockIdx.x & 1, wi = blockIdx.x >> 1;
    int hh  = blockIdx.y, n = blockIdx.z;
    int tid = threadIdx.x;
    int pbase = wi * 7 * 28 + wjp * 14;

    __shared__ __align__(16) char smem[51712];
    unsigned short* qS = (unsigned short*)smem;              // [2][64][40]
    unsigned short* kS = qS + 2 * 64 * 40;                   // [2][64][40]
    unsigned short* pS = (unsigned short*)smem;              // alias: [2][64][72]
    unsigned short* vT = (unsigned short*)(smem + 20480);    // [2][64][72]
    float*          posL = (float*)(smem + 20480 + 18432);   // [64][50]

    const unsigned short* Qu  = (const unsigned short*)Q;
    const unsigned short* KVu = (const unsigned short*)KV;

    // ---- load q, k: 2 bufs x 2 windows x 64 rows x 5 halves (zero-padded) ----
    for (int idx = tid; idx < 1280; idx += 256) {
        int which = idx >= 640 ? 1 : 0;
        int t2 = idx - which * 640;
        int w = t2 / 320, rm = t2 - w * 320;
        int row = rm / 5, half = rm - row * 5;
        uint4 v = make_uint4(0u, 0u, 0u, 0u);
        if (row < 49 && half < 2) {
            int p = pbase + (row / 7) * 28 + w * 7 + (row % 7);
            const unsigned short* src = which
                ? &KVu[((size_t)n * PP + p) * 384 + hh * 96 + 16 + half * 8]
                : &Qu[((size_t)n * PP + p) * 64 + hh * 16 + half * 8];
            v = *(const uint4*)src;
        }
        *(uint4*)((which ? kS : qS) + (w * 64 + row) * 40 + half * 8) = v;
    }
    // ---- stage V transposed: vT[w][d][ki], zero cols for ki >= 49 ----
    for (int idx = tid; idx < 1024; idx += 256) {
        int w = idx >> 9, rm = idx & 511;
        int ki = rm >> 3, dq = rm & 7;
        union { uint4 q; unsigned short h[8]; } v;
        v.q = make_uint4(0u, 0u, 0u, 0u);
        if (ki < 49) {
            int p = pbase + (ki / 7) * 28 + w * 7 + (ki % 7);
            v.q = *(const uint4*)&KVu[((size_t)n * PP + p) * 384 + hh * 96 + 32 + dq * 8];
        }
#pragma unroll
        for (int j = 0; j < 8; j++)
            vT[(w * 64 + dq * 8 + j) * 72 + ki] = v.h[j];
    }
    // ---- stage pos [64][50], zero-padded ----
    for (int idx = tid; idx < 3200; idx += 256) {
        int r = idx / 50, c = idx - r * 50;
        posL[idx] = (r < 49 && c < 49) ? pos[((size_t)hh * 49 + r) * 49 + c] : 0.f;
    }
    __syncthreads();

    int wv = tid >> 6, ln = tid & 63, l15 = ln & 15, quad = ln >> 4;

    // ---- S^T via MFMA + in-register softmax; hold packed bf16 P ----
    uint2 pk[2][4];
#pragma unroll
    for (int w = 0; w < 2; w++) {
        short8 qf = *(const short8*)&qS[(w * 64 + wv * 16 + l15) * 40 + quad * 8];
        floatx4 a4[4];
#pragma unroll
        for (int kt = 0; kt < 4; kt++) {
            short8 kf = *(const short8*)&kS[(w * 64 + kt * 16 + l15) * 40 + quad * 8];
            a4[kt] = __builtin_amdgcn_mfma_f32_16x16x32_bf16(
                kf, qf, (floatx4){0.f, 0.f, 0.f, 0.f}, 0, 0, 0);
        }
        int q = wv * 16 + l15;
        float sv[16];
        float m = -1e30f;
#pragma unroll
        for (int kt = 0; kt < 4; kt++) {
#pragma unroll
            for (int r = 0; r < 4; r++) {
                int ki = kt * 16 + quad * 4 + r;
                float sc = (ki < 49)
                    ? a4[kt][r] * 0.25f + posL[q * 50 + ki]
                    : -1e30f;
                sv[kt * 4 + r] = sc;
                m = fmaxf(m, sc);
            }
        }
        m = fmaxf(m, __shfl_xor(m, 16));
        m = fmaxf(m, __shfl_xor(m, 32));
        float sum = 0.f;
#pragma unroll
        for (int i = 0; i < 16; i++) { sv[i] = __expf(sv[i] - m); sum += sv[i]; }
        sum += __shfl_xor(sum, 16);
        sum += __shfl_xor(sum, 32);
        float inv = 1.f / sum;
#pragma unroll
        for (int kt = 0; kt < 4; kt++) {
            union { uint2 u; unsigned short h[4]; } pku;
#pragma unroll
            for (int r = 0; r < 4; r++) pku.h[r] = f2bits(sv[kt * 4 + r] * inv);
            pk[w][kt] = pku.u;
        }
    }
    __syncthreads();   // all qS/kS MFMA reads done before aliasing writes

    {
        int q = wv * 16 + l15;
#pragma unroll
        for (int w = 0; w < 2; w++)
#pragma unroll
            for (int kt = 0; kt < 4; kt++)
                *(uint2*)&pS[(w * 64 + q) * 72 + kt * 16 + quad * 4] = pk[w][kt];
    }
    __syncthreads();

    // ---- O = relu(P @ V) via MFMA ----
    unsigned short* Ou = (unsigned short*)O;
#pragma unroll
    for (int w = 0; w < 2; w++) {
        short8 af0 = *(const short8*)&pS[(w * 64 + wv * 16 + l15) * 72 + quad * 8];
        short8 af1 = *(const short8*)&pS[(w * 64 + wv * 16 + l15) * 72 + 32 + quad * 8];
#pragma unroll
        for (int dt = 0; dt < 4; dt++) {
            floatx4 oacc = (floatx4){0.f, 0.f, 0.f, 0.f};
            short8 vf0 = *(const short8*)&vT[(w * 64 + dt * 16 + l15) * 72 + quad * 8];
            short8 vf1 = *(const short8*)&vT[(w * 64 + dt * 16 + l15) * 72 + 32 + quad * 8];
            oacc = __builtin_amdgcn_mfma_f32_16x16x32_bf16(af0, vf0, oacc, 0, 0, 0);
            oacc = __builtin_amdgcn_mfma_f32_16x16x32_bf16(af1, vf1, oacc, 0, 0, 0);
#pragma unroll
            for (int r = 0; r < 4; r++) {
                int q = wv * 16 + quad * 4 + r;
                if (q < 49) {
                    int p = pbase + (q / 7) * 28 + w * 7 + (q % 7);
                    Ou[((size_t)n * PP + p) * 256 + hh * 64 + dt * 16 + l15] =
                        f2bits(fmaxf(oacc[r], 0.f));
                }
            }
        }
    }
}

// ---------------------------------------------------------------------------
extern "C" void kernel_launch(void* const* d_in, const int* in_sizes, int n_in,
                              void* d_out, int out_size, void* d_ws, size_t ws_size,
                              hipStream_t stream)
{
    const float* x0     = (const float*)d_in[0];
    const float* dw0_w  = (const float*)d_in[1];
    const float* dw0_s  = (const float*)d_in[2];
    const float* dw0_b  = (const float*)d_in[3];
    const float* dw1_w  = (const float*)d_in[4];
    const float* dw1_s  = (const float*)d_in[5];
    const float* dw1_b  = (const float*)d_in[6];
    const float* f0w1   = (const float*)d_in[7];
    const float* f0s1   = (const float*)d_in[8];
    const float* f0b1   = (const float*)d_in[9];
    const float* f0w2   = (const float*)d_in[10];
    const float* f0s2   = (const float*)d_in[11];
    const float* f0b2   = (const float*)d_in[12];
    const float* f1w1   = (const float*)d_in[13];
    const float* f1s1   = (const float*)d_in[14];
    const float* f1b1   = (const float*)d_in[15];
    const float* f1w2   = (const float*)d_in[16];
    const float* f1s2   = (const float*)d_in[17];
    const float* f1b2   = (const float*)d_in[18];
    const float* qkv_w  = (const float*)d_in[19];
    const float* qkv_s  = (const float*)d_in[20];
    const float* qkv_b  = (const float*)d_in[21];
    const float* dws_w  = (const float*)d_in[22];
    const float* dws_s  = (const float*)d_in[23];
    const float* dws_b  = (const float*)d_in[24];
    const float* proj_w = (const float*)d_in[25];
    const float* proj_s = (const float*)d_in[26];
    const float* proj_b = (const float*)d_in[27];
    const float* pos    = (const float*)d_in[28];

    // -------- workspace (aliased, same proven scheme; Hb now unused) --------
    const size_t NXB = (size_t)BB * DIMC * PP * 4;    // 51,380,224 B
    char* base  = (char*)d_ws;
    float* X1   = (float*)base;
    bf16*  Qb   = (bf16*)(base + NXB);
    char*  C_   = base + 2 * NXB;
    bf16*  QKVb = (bf16*)C_;
    float* X2   = (float*)C_;                          // alias, disjoint in time
    bf16*  X1b  = (bf16*)(base + 3 * NXB);             // 25.7 MB
    bf16*  Wc   = (bf16*)(base + 3 * NXB + NXB / 2);
    bf16*  Ob   = (bf16*)d_out;
    float* outp = (float*)d_out;

    bf16* Wf0w1 = Wc;                  // [512][256]
    bf16* Wf0w2 = Wf0w1 + 131072;      // [256][512]
    bf16* Wf1w1 = Wf0w2 + 131072;      // [512][256]
    bf16* Wf1w2 = Wf1w1 + 131072;      // [256][512]
    bf16* Wqkv  = Wf1w2 + 131072;      // [384][256]
    bf16* Wproj = Wqkv + 98304;        // [256][256]

    dim3 blk(256);

    // 0) weights fp32 -> bf16 (single merged launch)
    cvt_all<<<2688, blk, 0, stream>>>(f0w1, Wf0w1, f0w2, Wf0w2,
                                      f1w1, Wf1w1, f1w2, Wf1w2,
                                      qkv_w, Wqkv, proj_w, Wproj);

    // 1) x = x + dw0(x); mirror to NHWC bf16
    dw3x3_kernel<<<dim3(BB, DIMC / CPB), blk, 0, stream>>>(x0, dw0_w, dw0_s, dw0_b, X1);
    tr_cvt<<<dim3(25, 8, BB), blk, 0, stream>>>(X1, X1b);

    // 2-3) ffn0 fused (refreshes both X1 fp32 and X1b NHWC; Hb eliminated)
    ffn_fused<2><<<dim3(13, BB), blk, 0, stream>>>(
        Wf0w1, f0s1, f0b1, Wf0w2, f0s2, f0b2, X1b, X1, X1, X1b);

    // 4-7) attention
    gemm_mfma<false, false, 0><<<dim3(7, 384 / 64, BB), blk, 0, stream>>>(
        Wqkv, X1b, qkv_s, qkv_b, nullptr, nullptr, QKVb, 384, DIMC);
    dws5x5_nhwc<<<dim3(NHH, BB), blk, 0, stream>>>(QKVb, dws_w, dws_s, dws_b, Qb);
    attn_kernel<<<dim3(8, NHH, BB), blk, 0, stream>>>(Qb, QKVb, pos, Ob);
    gemm_mfma<false, true, 1><<<dim3(7, DIMC / 64, BB), blk, 0, stream>>>(
        Wproj, Ob, proj_s, proj_b, X1, X1, nullptr, DIMC, DIMC);

    // 8) x = x + dw1(x)  (QKVb dead -> X2); mirror to NHWC bf16 (reuse X1b)
    dw3x3_kernel<<<dim3(BB, DIMC / CPB), blk, 0, stream>>>(X1, dw1_w, dw1_s, dw1_b, X2);
    tr_cvt<<<dim3(25, 8, BB), blk, 0, stream>>>(X2, X1b);

    // 9-10) ffn1 fused, final fp32 NCHW to d_out
    ffn_fused<1><<<dim3(13, BB), blk, 0, stream>>>(
        Wf1w1, f1s1, f1b1, Wf1w2, f1s2, f1b2, X1b, X2, outp, nullptr);
}

// Round 8
// 554.141 us; speedup vs baseline: 1.3063x; 1.3063x over previous
//
#include <hip/hip_runtime.h>
#include <hip/hip_bf16.h>
#include <math.h>

typedef __hip_bfloat16 bf16;
typedef __attribute__((ext_vector_type(8))) short short8;   // 8 x bf16 MFMA frag
typedef __attribute__((ext_vector_type(4))) float floatx4;  // 4 x f32 MFMA acc

// Problem constants: B=64, DIM=256, HID=512, NH=4, KD=16, D=64, 28x28, WH=7
#define BB    64
#define DIMC  256
#define HIDC  512
#define NHH   4
#define HH_   28
#define WW_   28
#define PP    784   // 28*28

__device__ __forceinline__ float toF(bf16 x) { return __bfloat162float(x); }
__device__ __forceinline__ unsigned short f2bits(float f) {
    union { bf16 h; unsigned short u; } cv; cv.h = __float2bfloat16(f); return cv.u;
}
__device__ __forceinline__ float bits2f(unsigned short u) {
    union { unsigned int u32; float f; } cv; cv.u32 = ((unsigned int)u) << 16; return cv.f;
}

// async 16B global -> LDS (wave-uniform LDS base + lane*16; vmcnt-counted)
__device__ __forceinline__ void gll16(const void* g, void* l) {
    __builtin_amdgcn_global_load_lds(
        (const __attribute__((address_space(1))) void*)g,
        (__attribute__((address_space(3))) void*)l, 16, 0, 0);
}

// ---------------------------------------------------------------------------
// fp32 -> bf16 weight convert — single merged launch for all 6 weight arrays
// ---------------------------------------------------------------------------
__global__ __launch_bounds__(256) void cvt_all(
    const float* __restrict__ s0, bf16* __restrict__ d0,   // 131072
    const float* __restrict__ s1, bf16* __restrict__ d1,   // 131072
    const float* __restrict__ s2, bf16* __restrict__ d2,   // 131072
    const float* __restrict__ s3, bf16* __restrict__ d3,   // 131072
    const float* __restrict__ s4, bf16* __restrict__ d4,   // 98304
    const float* __restrict__ s5, bf16* __restrict__ d5)   // 65536
{
    int i = blockIdx.x * 256 + threadIdx.x;
    if (i < 131072)                d0[i]          = __float2bfloat16(s0[i]);
    else if (i < 262144)           d1[i - 131072] = __float2bfloat16(s1[i - 131072]);
    else if (i < 393216)           d2[i - 262144] = __float2bfloat16(s2[i - 262144]);
    else if (i < 524288)           d3[i - 393216] = __float2bfloat16(s3[i - 393216]);
    else if (i < 622592)           d4[i - 524288] = __float2bfloat16(s4[i - 524288]);
    else if (i < 688128)           d5[i - 622592] = __float2bfloat16(s5[i - 622592]);
}

// ---------------------------------------------------------------------------
// fp32 NCHW [64][256][784] -> bf16 NHWC [64][784][256] (LDS 32x32 transpose)
// grid (25, 8, 64), block 256
// ---------------------------------------------------------------------------
__global__ __launch_bounds__(256) void tr_cvt(
    const float* __restrict__ in, bf16* __restrict__ out)
{
    __shared__ float t[32][33];
    int n  = blockIdx.z;
    int p0 = blockIdx.x * 32;
    int c0 = blockIdx.y * 32;
    int tx = threadIdx.x & 31;
    int ty = threadIdx.x >> 5;   // 0..7
#pragma unroll
    for (int e = 0; e < 4; e++) {
        int c = c0 + ty + e * 8;
        int p = p0 + tx;
        if (p < PP) t[ty + e * 8][tx] = in[((size_t)n * DIMC + c) * PP + p];
    }
    __syncthreads();
#pragma unroll
    for (int e = 0; e < 4; e++) {
        int p = p0 + ty + e * 8;
        int c = c0 + tx;
        if (p < PP) out[((size_t)n * PP + p) * DIMC + c] = __float2bfloat16(t[tx][ty + e * 8]);
    }
}

// ---------------------------------------------------------------------------
// Depthwise 3x3 conv + BN + residual (NCHW fp32) — round-0 LDS version.
// ---------------------------------------------------------------------------
#define CPB 4
__global__ __launch_bounds__(256) void dw3x3_kernel(
    const float* __restrict__ in, const float* __restrict__ w,
    const float* __restrict__ s, const float* __restrict__ b,
    float* __restrict__ out)
{
    __shared__ float t[CPB][30 * 30];        // padded planes, zero halo
    __shared__ float wS[CPB * 9 + 2 * CPB];  // 9 weights + scale + bias per ch

    int n   = blockIdx.x;
    int c0  = blockIdx.y * CPB;
    int tid = threadIdx.x;
    const float* ip = in  + ((size_t)n * DIMC + c0) * PP;
    float*       op = out + ((size_t)n * DIMC + c0) * PP;

    // weights/scale/bias -> LDS
    if (tid < CPB * 9)                wS[tid] = w[c0 * 9 + tid];
    else if (tid < CPB * 10)          wS[tid] = s[c0 + tid - CPB * 9];
    else if (tid < CPB * 11)          wS[tid] = b[c0 + tid - CPB * 10];

    // zero-fill padded planes (halo must be 0; interior overwritten below)
    for (int i = tid; i < CPB * 900; i += 256) ((float*)t)[i] = 0.f;
    __syncthreads();

    // stage: CPB*196 float4 tasks; each row of 28 = 7 aligned float4
    for (int idx = tid; idx < CPB * 196; idx += 256) {
        int ch  = idx / 196;
        int rm  = idx - ch * 196;
        int row = rm / 7, seg = rm - row * 7;
        float4 v = *(const float4*)&ip[ch * PP + row * 28 + seg * 4];
        float* dst = &t[ch][(row + 1) * 30 + seg * 4 + 1];
        dst[0] = v.x; dst[1] = v.y; dst[2] = v.z; dst[3] = v.w;
    }
    __syncthreads();

    // compute: 4-px segments; padded window rows row..row+2, cols x0..x0+5
    for (int idx = tid; idx < CPB * 196; idx += 256) {
        int ch  = idx / 196;
        int rm  = idx - ch * 196;
        int row = rm / 7, seg = rm - row * 7;
        int x0  = seg * 4;
        float w9[9];
#pragma unroll
        for (int i = 0; i < 9; i++) w9[i] = wS[ch * 9 + i];
        float sc = wS[CPB * 9 + ch], bb = wS[CPB * 10 + ch];

        float acc[4] = {0.f, 0.f, 0.f, 0.f};
        float ctr[4];
        const float* base = &t[ch][row * 30 + x0];
#pragma unroll
        for (int i = 0; i < 3; i++) {
            float r[6];
#pragma unroll
            for (int k = 0; k < 6; k++) r[k] = base[i * 30 + k];
            if (i == 1) { ctr[0] = r[1]; ctr[1] = r[2]; ctr[2] = r[3]; ctr[3] = r[4]; }
#pragma unroll
            for (int j = 0; j < 3; j++)
#pragma unroll
                for (int q = 0; q < 4; q++)
                    acc[q] += w9[i * 3 + j] * r[j + q];
        }
        float4 o;
        o.x = ctr[0] + acc[0] * sc + bb;
        o.y = ctr[1] + acc[1] * sc + bb;
        o.z = ctr[2] + acc[2] * sc + bb;
        o.w = ctr[3] + acc[3] * sc + bb;
        *(float4*)&op[ch * PP + row * 28 + x0] = o;
    }
}

// ---------------------------------------------------------------------------
// Per-head depthwise 5x5 + BN on q channels — round-5 LDS version (proven).
// grid (NHH, BB), block 256, LDS 32 KB.
// ---------------------------------------------------------------------------
__global__ __launch_bounds__(256) void dws5x5_nhwc(
    const bf16* __restrict__ qkv,   // [64][784][384]
    const float* __restrict__ w,    // [64][25]  (hk-major)
    const float* __restrict__ s, const float* __restrict__ b,
    bf16* __restrict__ qout)        // [64][784][64]
{
    __shared__ __align__(16) unsigned short qin[32 * 32 * 16];  // [r][c][ch]
    int hh  = blockIdx.x;
    int n   = blockIdx.y;
    int tid = threadIdx.x;
    const unsigned short* KVu = (const unsigned short*)qkv;

    int kcw = tid & 15;
    int hk  = hh * 16 + kcw;
    float w25[25];
#pragma unroll
    for (int i = 0; i < 25; i++) w25[i] = w[hk * 25 + i];
    float csc = s[hk], cbb = b[hk];

    // zero-fill (halo must be 0), then stage interior
    for (int i = tid; i < 4096; i += 256)
        ((uint4*)qin)[i] = make_uint4(0u, 0u, 0u, 0u);
    __syncthreads();
    for (int idx = tid; idx < 1568; idx += 256) {
        int p = idx >> 1, half = idx & 1;
        int h = p / 28, x = p - h * 28;
        uint4 v = *(const uint4*)&KVu[((size_t)n * PP + p) * 384 + hh * 96 + half * 8];
        *(uint4*)&qin[((h + 2) * 32 + (x + 2)) * 16 + half * 8] = v;
    }
    __syncthreads();

    // compute: 784 px x 16 ch tasks
    for (int idx = tid; idx < 12544; idx += 256) {
        int p = idx >> 4;            // channel == kcw since 256 % 16 == 0
        int h = p / 28, x = p - h * 28;
        float acc = 0.f;
#pragma unroll
        for (int i = 0; i < 5; i++)
#pragma unroll
            for (int j = 0; j < 5; j++)
                acc += w25[i * 5 + j] * bits2f(qin[((h + i) * 32 + (x + j)) * 16 + kcw]);
        qout[((size_t)n * PP + p) * 64 + hk] = __float2bfloat16(acc * csc + cbb);
    }
}

// ---------------------------------------------------------------------------
// 1x1 conv as bf16 MFMA GEMM — ROUND-7: global_load_lds direct staging.
// Changes vs round-3 (ffn_fused round-6 REVERTED):
//  - X tile staged via __builtin_amdgcn_global_load_lds width=16 (no VGPR
//    round-trip; m151: +35% vs reg staging at this tile size).
//  - Linear LDS rows (64 B) with chunk XOR-swizzle ((row>>1)&3), applied on
//    the GLOBAL source (write side) and the ds_read addr (read side) — rule
//    #21 both-sides involution; 16 rows -> 8 slots -> 2-way aliasing (free).
//  - ONE barrier per K-step: iter t stages buf[t^1], computes buf[t],
//    barrier. Barrier at end of t orders all reads of buf[t] before iter
//    t+1's writes to it; syncthreads' vmcnt(0) drain completes the stage.
// Tile 64(co) x 112(p), K-step 32, 4 waves. LDS 2 x 7 KB.
// OUTMODE: 0 = bf16 NHWC; 1 = fp32 NCHW; 2 = both.   grid (7, M/64, 64)
// ---------------------------------------------------------------------------
template <bool RELU, bool RES, int OUTMODE>
__global__ __launch_bounds__(256) void gemm_mfma(
    const bf16* __restrict__ Wb,    // [M][K] bf16
    const bf16* __restrict__ X,     // [64][784][K] bf16 NHWC
    const float* __restrict__ S, const float* __restrict__ Bb,
    const float* __restrict__ res,  // [64][M][784] fp32 NCHW (if RES)
    float* __restrict__ outF,       // fp32 NCHW (OUTMODE 1/2)
    bf16*  __restrict__ outB,       // bf16 NHWC (OUTMODE 0/2)
    int M, int K)
{
    int n    = blockIdx.z;
    int co0  = blockIdx.y * 64;
    int p0   = blockIdx.x * 112;
    int tid  = threadIdx.x;
    int wv   = tid >> 6;
    int ln   = tid & 63;
    int l15  = ln & 15;
    int quad = ln >> 4;

    __shared__ __align__(16) unsigned short Blds[2][112 * 32];  // linear 64B rows

    floatx4 acc[7];
#pragma unroll
    for (int t = 0; t < 7; t++) acc[t] = (floatx4){0.f, 0.f, 0.f, 0.f};

    const bf16* Arow = Wb + (size_t)(co0 + wv * 16 + l15) * K + quad * 8;
    const unsigned short* Xb = (const unsigned short*)X + ((size_t)n * PP + p0) * K;

    // staging geometry: issue A covers rows 0..63 (all waves), issue B rows
    // 64..111 (waves 0..2). dest = wave-uniform LDS base + lane*16.
    int rA = wv * 16 + (ln >> 2);            // 0..63
    int rB = 64 + wv * 16 + (ln >> 2);       // 64..111 (wv<3)
    int cA = (ln & 3) ^ ((rA >> 1) & 3);     // pre-swizzled source chunk
    int cB = (ln & 3) ^ ((rB >> 1) & 3);
    const unsigned short* gA = Xb + (size_t)rA * K + cA * 8;
    const unsigned short* gB = Xb + (size_t)rB * K + cB * 8;

    // prologue: stage tile 0
    gll16(gA, &Blds[0][(wv * 16) * 32]);
    if (wv < 3) gll16(gB, &Blds[0][(64 + wv * 16) * 32]);
    short8 af = *(const short8*)Arow;
    __syncthreads();

    int NT = K >> 5;
    for (int t = 0; t < NT; t++) {
        int cur = t & 1;
        short8 naf = af;
        if (t + 1 < NT) {
            gll16(gA + (t + 1) * 32, &Blds[cur ^ 1][(wv * 16) * 32]);
            if (wv < 3) gll16(gB + (t + 1) * 32, &Blds[cur ^ 1][(64 + wv * 16) * 32]);
            naf = *(const short8*)(Arow + (t + 1) * 32);
        }
#pragma unroll
        for (int tt = 0; tt < 7; tt++) {
            int row = tt * 16 + l15;
            short8 bfrag = *(const short8*)
                &Blds[cur][row * 32 + ((quad ^ ((row >> 1) & 3)) * 8)];
            acc[tt] = __builtin_amdgcn_mfma_f32_16x16x32_bf16(af, bfrag, acc[tt], 0, 0, 0);
        }
        af = naf;
        __syncthreads();   // vmcnt(0) drain (stage done) + reads of buf[cur] done
    }

    int cobase = co0 + wv * 16 + quad * 4;
    float s4[4], b4[4];
#pragma unroll
    for (int r = 0; r < 4; r++) { s4[r] = S[cobase + r]; b4[r] = Bb[cobase + r]; }

#pragma unroll
    for (int t = 0; t < 7; t++) {
        int p = p0 + t * 16 + l15;   // always < 784
        float y[4];
#pragma unroll
        for (int r = 0; r < 4; r++) {
            y[r] = acc[t][r] * s4[r] + b4[r];
            if (RELU) y[r] = fmaxf(y[r], 0.f);
            if (RES) y[r] += res[((size_t)n * M + cobase + r) * PP + p];
        }
        if (OUTMODE == 1 || OUTMODE == 2) {
#pragma unroll
            for (int r = 0; r < 4; r++)
                outF[((size_t)n * M + cobase + r) * PP + p] = y[r];
        }
        if (OUTMODE == 0 || OUTMODE == 2) {
            union { unsigned short h4[4]; uint2 u; } pk;
#pragma unroll
            for (int r = 0; r < 4; r++) pk.h4[r] = f2bits(y[r]);
            *(uint2*)((unsigned short*)outB + ((size_t)n * PP + p) * M + cobase) = pk.u;
        }
    }
}

// ---------------------------------------------------------------------------
// 7x7 window attention — round-1 MFMA version (proven).
// grid (8, 4, 64), block 256.
// ---------------------------------------------------------------------------
__global__ __launch_bounds__(256) void attn_kernel(
    const bf16*  __restrict__ Q,       // [64][784][64] NHWC (hk = hh*16+kc)
    const bf16*  __restrict__ KV,      // [64][784][384] NHWC
    const float* __restrict__ pos,     // [4][49][49]
    bf16* __restrict__ O)              // [64][784][256] NHWC (c = hh*64+d)
{
    int wjp = blockIdx.x & 1, wi = blockIdx.x >> 1;
    int hh  = blockIdx.y, n = blockIdx.z;
    int tid = threadIdx.x;
    int pbase = wi * 7 * 28 + wjp * 14;

    __shared__ __align__(16) char smem[51712];
    unsigned short* qS = (unsigned short*)smem;              // [2][64][40]
    unsigned short* kS = qS + 2 * 64 * 40;                   // [2][64][40]
    unsigned short* pS = (unsigned short*)smem;              // alias: [2][64][72]
    unsigned short* vT = (unsigned short*)(smem + 20480);    // [2][64][72]
    float*          posL = (float*)(smem + 20480 + 18432);   // [64][50]

    const unsigned short* Qu  = (const unsigned short*)Q;
    const unsigned short* KVu = (const unsigned short*)KV;

    // ---- load q, k: 2 bufs x 2 windows x 64 rows x 5 halves (zero-padded) ----
    for (int idx = tid; idx < 1280; idx += 256) {
        int which = idx >= 640 ? 1 : 0;
        int t2 = idx - which * 640;
        int w = t2 / 320, rm = t2 - w * 320;
        int row = rm / 5, half = rm - row * 5;
        uint4 v = make_uint4(0u, 0u, 0u, 0u);
        if (row < 49 && half < 2) {
            int p = pbase + (row / 7) * 28 + w * 7 + (row % 7);
            const unsigned short* src = which
                ? &KVu[((size_t)n * PP + p) * 384 + hh * 96 + 16 + half * 8]
                : &Qu[((size_t)n * PP + p) * 64 + hh * 16 + half * 8];
            v = *(const uint4*)src;
        }
        *(uint4*)((which ? kS : qS) + (w * 64 + row) * 40 + half * 8) = v;
    }
    // ---- stage V transposed: vT[w][d][ki], zero cols for ki >= 49 ----
    for (int idx = tid; idx < 1024; idx += 256) {
        int w = idx >> 9, rm = idx & 511;
        int ki = rm >> 3, dq = rm & 7;
        union { uint4 q; unsigned short h[8]; } v;
        v.q = make_uint4(0u, 0u, 0u, 0u);
        if (ki < 49) {
            int p = pbase + (ki / 7) * 28 + w * 7 + (ki % 7);
            v.q = *(const uint4*)&KVu[((size_t)n * PP + p) * 384 + hh * 96 + 32 + dq * 8];
        }
#pragma unroll
        for (int j = 0; j < 8; j++)
            vT[(w * 64 + dq * 8 + j) * 72 + ki] = v.h[j];
    }
    // ---- stage pos [64][50], zero-padded ----
    for (int idx = tid; idx < 3200; idx += 256) {
        int r = idx / 50, c = idx - r * 50;
        posL[idx] = (r < 49 && c < 49) ? pos[((size_t)hh * 49 + r) * 49 + c] : 0.f;
    }
    __syncthreads();

    int wv = tid >> 6, ln = tid & 63, l15 = ln & 15, quad = ln >> 4;

    // ---- S^T via MFMA + in-register softmax; hold packed bf16 P ----
    uint2 pk[2][4];
#pragma unroll
    for (int w = 0; w < 2; w++) {
        short8 qf = *(const short8*)&qS[(w * 64 + wv * 16 + l15) * 40 + quad * 8];
        floatx4 a4[4];
#pragma unroll
        for (int kt = 0; kt < 4; kt++) {
            short8 kf = *(const short8*)&kS[(w * 64 + kt * 16 + l15) * 40 + quad * 8];
            a4[kt] = __builtin_amdgcn_mfma_f32_16x16x32_bf16(
                kf, qf, (floatx4){0.f, 0.f, 0.f, 0.f}, 0, 0, 0);
        }
        int q = wv * 16 + l15;
        float sv[16];
        float m = -1e30f;
#pragma unroll
        for (int kt = 0; kt < 4; kt++) {
#pragma unroll
            for (int r = 0; r < 4; r++) {
                int ki = kt * 16 + quad * 4 + r;
                float sc = (ki < 49)
                    ? a4[kt][r] * 0.25f + posL[q * 50 + ki]
                    : -1e30f;
                sv[kt * 4 + r] = sc;
                m = fmaxf(m, sc);
            }
        }
        m = fmaxf(m, __shfl_xor(m, 16));
        m = fmaxf(m, __shfl_xor(m, 32));
        float sum = 0.f;
#pragma unroll
        for (int i = 0; i < 16; i++) { sv[i] = __expf(sv[i] - m); sum += sv[i]; }
        sum += __shfl_xor(sum, 16);
        sum += __shfl_xor(sum, 32);
        float inv = 1.f / sum;
#pragma unroll
        for (int kt = 0; kt < 4; kt++) {
            union { uint2 u; unsigned short h[4]; } pku;
#pragma unroll
            for (int r = 0; r < 4; r++) pku.h[r] = f2bits(sv[kt * 4 + r] * inv);
            pk[w][kt] = pku.u;
        }
    }
    __syncthreads();   // all qS/kS MFMA reads done before aliasing writes

    {
        int q = wv * 16 + l15;
#pragma unroll
        for (int w = 0; w < 2; w++)
#pragma unroll
            for (int kt = 0; kt < 4; kt++)
                *(uint2*)&pS[(w * 64 + q) * 72 + kt * 16 + quad * 4] = pk[w][kt];
    }
    __syncthreads();

    // ---- O = relu(P @ V) via MFMA ----
    unsigned short* Ou = (unsigned short*)O;
#pragma unroll
    for (int w = 0; w < 2; w++) {
        short8 af0 = *(const short8*)&pS[(w * 64 + wv * 16 + l15) * 72 + quad * 8];
        short8 af1 = *(const short8*)&pS[(w * 64 + wv * 16 + l15) * 72 + 32 + quad * 8];
#pragma unroll
        for (int dt = 0; dt < 4; dt++) {
            floatx4 oacc = (floatx4){0.f, 0.f, 0.f, 0.f};
            short8 vf0 = *(const short8*)&vT[(w * 64 + dt * 16 + l15) * 72 + quad * 8];
            short8 vf1 = *(const short8*)&vT[(w * 64 + dt * 16 + l15) * 72 + 32 + quad * 8];
            oacc = __builtin_amdgcn_mfma_f32_16x16x32_bf16(af0, vf0, oacc, 0, 0, 0);
            oacc = __builtin_amdgcn_mfma_f32_16x16x32_bf16(af1, vf1, oacc, 0, 0, 0);
#pragma unroll
            for (int r = 0; r < 4; r++) {
                int q = wv * 16 + quad * 4 + r;
                if (q < 49) {
                    int p = pbase + (q / 7) * 28 + w * 7 + (q % 7);
                    Ou[((size_t)n * PP + p) * 256 + hh * 64 + dt * 16 + l15] =
                        f2bits(fmaxf(oacc[r], 0.f));
                }
            }
        }
    }
}

// ---------------------------------------------------------------------------
extern "C" void kernel_launch(void* const* d_in, const int* in_sizes, int n_in,
                              void* d_out, int out_size, void* d_ws, size_t ws_size,
                              hipStream_t stream)
{
    const float* x0     = (const float*)d_in[0];
    const float* dw0_w  = (const float*)d_in[1];
    const float* dw0_s  = (const float*)d_in[2];
    const float* dw0_b  = (const float*)d_in[3];
    const float* dw1_w  = (const float*)d_in[4];
    const float* dw1_s  = (const float*)d_in[5];
    const float* dw1_b  = (const float*)d_in[6];
    const float* f0w1   = (const float*)d_in[7];
    const float* f0s1   = (const float*)d_in[8];
    const float* f0b1   = (const float*)d_in[9];
    const float* f0w2   = (const float*)d_in[10];
    const float* f0s2   = (const float*)d_in[11];
    const float* f0b2   = (const float*)d_in[12];
    const float* f1w1   = (const float*)d_in[13];
    const float* f1s1   = (const float*)d_in[14];
    const float* f1b1   = (const float*)d_in[15];
    const float* f1w2   = (const float*)d_in[16];
    const float* f1s2   = (const float*)d_in[17];
    const float* f1b2   = (const float*)d_in[18];
    const float* qkv_w  = (const float*)d_in[19];
    const float* qkv_s  = (const float*)d_in[20];
    const float* qkv_b  = (const float*)d_in[21];
    const float* dws_w  = (const float*)d_in[22];
    const float* dws_s  = (const float*)d_in[23];
    const float* dws_b  = (const float*)d_in[24];
    const float* proj_w = (const float*)d_in[25];
    const float* proj_s = (const float*)d_in[26];
    const float* proj_b = (const float*)d_in[27];
    const float* pos    = (const float*)d_in[28];

    // -------- workspace (aliased, same proven scheme) --------
    const size_t NXB = (size_t)BB * DIMC * PP * 4;    // 51,380,224 B
    char* base  = (char*)d_ws;
    float* X1   = (float*)base;
    bf16*  Hb   = (bf16*)(base + NXB);
    bf16*  Qb   = Hb;                                  // alias, disjoint in time
    char*  C_   = base + 2 * NXB;
    bf16*  QKVb = (bf16*)C_;
    float* X2   = (float*)C_;                          // alias, disjoint in time
    bf16*  X1b  = (bf16*)(base + 3 * NXB);             // 25.7 MB
    bf16*  Wc   = (bf16*)(base + 3 * NXB + NXB / 2);
    bf16*  Ob   = (bf16*)d_out;
    float* outp = (float*)d_out;

    bf16* Wf0w1 = Wc;                  // [512][256]
    bf16* Wf0w2 = Wf0w1 + 131072;      // [256][512]
    bf16* Wf1w1 = Wf0w2 + 131072;      // [512][256]
    bf16* Wf1w2 = Wf1w1 + 131072;      // [256][512]
    bf16* Wqkv  = Wf1w2 + 131072;      // [384][256]
    bf16* Wproj = Wqkv + 98304;        // [256][256]

    dim3 blk(256);

    // 0) weights fp32 -> bf16 (single merged launch)
    cvt_all<<<2688, blk, 0, stream>>>(f0w1, Wf0w1, f0w2, Wf0w2,
                                      f1w1, Wf1w1, f1w2, Wf1w2,
                                      qkv_w, Wqkv, proj_w, Wproj);

    // 1) x = x + dw0(x); mirror to NHWC bf16
    dw3x3_kernel<<<dim3(BB, DIMC / CPB), blk, 0, stream>>>(x0, dw0_w, dw0_s, dw0_b, X1);
    tr_cvt<<<dim3(25, 8, BB), blk, 0, stream>>>(X1, X1b);

    // 2-3) ffn0 (second GEMM refreshes both X1 fp32 and X1b NHWC)
    gemm_mfma<true, false, 0><<<dim3(7, HIDC / 64, BB), blk, 0, stream>>>(
        Wf0w1, X1b, f0s1, f0b1, nullptr, nullptr, Hb, HIDC, DIMC);
    gemm_mfma<false, true, 2><<<dim3(7, DIMC / 64, BB), blk, 0, stream>>>(
        Wf0w2, Hb, f0s2, f0b2, X1, X1, X1b, DIMC, HIDC);

    // 4-7) attention
    gemm_mfma<false, false, 0><<<dim3(7, 384 / 64, BB), blk, 0, stream>>>(
        Wqkv, X1b, qkv_s, qkv_b, nullptr, nullptr, QKVb, 384, DIMC);
    dws5x5_nhwc<<<dim3(NHH, BB), blk, 0, stream>>>(QKVb, dws_w, dws_s, dws_b, Qb);
    attn_kernel<<<dim3(8, NHH, BB), blk, 0, stream>>>(Qb, QKVb, pos, Ob);
    gemm_mfma<false, true, 1><<<dim3(7, DIMC / 64, BB), blk, 0, stream>>>(
        Wproj, Ob, proj_s, proj_b, X1, X1, nullptr, DIMC, DIMC);

    // 8) x = x + dw1(x)  (QKVb dead -> X2); mirror to NHWC bf16 (reuse X1b)
    dw3x3_kernel<<<dim3(BB, DIMC / CPB), blk, 0, stream>>>(X1, dw1_w, dw1_s, dw1_b, X2);
    tr_cvt<<<dim3(25, 8, BB), blk, 0, stream>>>(X2, X1b);

    // 9-10) ffn1, final fp32 NCHW to d_out
    gemm_mfma<true, false, 0><<<dim3(7, HIDC / 64, BB), blk, 0, stream>>>(
        Wf1w1, X1b, f1s1, f1b1, nullptr, nullptr, Hb, HIDC, DIMC);
    gemm_mfma<false, true, 1><<<dim3(7, DIMC / 64, BB), blk, 0, stream>>>(
        Wf1w2, Hb, f1s2, f1b2, X2, outp, nullptr, DIMC, HIDC);
}

// Round 10
// 472.587 us; speedup vs baseline: 1.5317x; 1.1726x over previous
//
#include <hip/hip_runtime.h>
#include <hip/hip_bf16.h>
#include <math.h>

typedef __hip_bfloat16 bf16;
typedef __attribute__((ext_vector_type(8))) short short8;   // 8 x bf16 MFMA frag
typedef __attribute__((ext_vector_type(4))) float floatx4;  // 4 x f32 MFMA acc

// Problem constants: B=64, DIM=256, HID=512, NH=4, KD=16, D=64, 28x28, WH=7
#define BB    64
#define DIMC  256
#define HIDC  512
#define NHH   4
#define HH_   28
#define WW_   28
#define PP    784   // 28*28

__device__ __forceinline__ float toF(bf16 x) { return __bfloat162float(x); }
__device__ __forceinline__ unsigned short f2bits(float f) {
    union { bf16 h; unsigned short u; } cv; cv.h = __float2bfloat16(f); return cv.u;
}
__device__ __forceinline__ float bits2f(unsigned short u) {
    union { unsigned int u32; float f; } cv; cv.u32 = ((unsigned int)u) << 16; return cv.f;
}

// async 16B global -> LDS (wave-uniform LDS base + lane*16; vmcnt-counted)
__device__ __forceinline__ void gll16(const void* g, void* l) {
    __builtin_amdgcn_global_load_lds(
        (const __attribute__((address_space(1))) void*)g,
        (__attribute__((address_space(3))) void*)l, 16, 0, 0);
}

// ---------------------------------------------------------------------------
// fp32 -> bf16 weight convert — single merged launch for all 6 weight arrays
// ---------------------------------------------------------------------------
__global__ __launch_bounds__(256) void cvt_all(
    const float* __restrict__ s0, bf16* __restrict__ d0,   // 131072
    const float* __restrict__ s1, bf16* __restrict__ d1,   // 131072
    const float* __restrict__ s2, bf16* __restrict__ d2,   // 131072
    const float* __restrict__ s3, bf16* __restrict__ d3,   // 131072
    const float* __restrict__ s4, bf16* __restrict__ d4,   // 98304
    const float* __restrict__ s5, bf16* __restrict__ d5)   // 65536
{
    int i = blockIdx.x * 256 + threadIdx.x;
    if (i < 131072)                d0[i]          = __float2bfloat16(s0[i]);
    else if (i < 262144)           d1[i - 131072] = __float2bfloat16(s1[i - 131072]);
    else if (i < 393216)           d2[i - 262144] = __float2bfloat16(s2[i - 262144]);
    else if (i < 524288)           d3[i - 393216] = __float2bfloat16(s3[i - 393216]);
    else if (i < 622592)           d4[i - 524288] = __float2bfloat16(s4[i - 524288]);
    else if (i < 688128)           d5[i - 622592] = __float2bfloat16(s5[i - 622592]);
}

// ---------------------------------------------------------------------------
// Depthwise 3x3 conv + BN + residual — ROUND-8: now ALSO writes the bf16 NHWC
// mirror (tr_cvt deleted: it only re-read 51.4 MB to cast the same values).
// Mirror = bf16(same fp32) -> bit-identical to the old tr_cvt output.
// Physical blocks remapped via chunked-XCD bijection so the 64 channel-groups
// of one image are co-XCD: their 8B NHWC chunks assemble full cache lines in
// one L2. LDS: planes 14.4 KB + outL 12.5 KB -> ~6 blocks/CU.
// grid (64 cgroups, BB), block 256.
// ---------------------------------------------------------------------------
#define CPB 4
__global__ __launch_bounds__(256) void dw3x3_kernel(
    const float* __restrict__ in, const float* __restrict__ w,
    const float* __restrict__ s, const float* __restrict__ b,
    float* __restrict__ out, bf16* __restrict__ outB)
{
    __shared__ float t[CPB][30 * 30];        // padded planes, zero halo
    __shared__ float wS[CPB * 9 + 2 * CPB];  // 9 weights + scale + bias per ch
    __shared__ float outL[CPB][784];         // results for NHWC pack

    // chunked-XCD bijective remap: physical wid -> logical (n, cgroup),
    // cgroup fastest so one image's 64 cgroups are contiguous on one XCD.
    int wid = blockIdx.y * gridDim.x + blockIdx.x;         // 0..4095
    int lin = (wid & 7) * 512 + (wid >> 3);                // 4096/8 = 512
    int cg  = lin & 63;
    int n   = lin >> 6;
    int c0  = cg * CPB;

    int tid = threadIdx.x;
    const float* ip = in  + ((size_t)n * DIMC + c0) * PP;
    float*       op = out + ((size_t)n * DIMC + c0) * PP;

    // weights/scale/bias -> LDS
    if (tid < CPB * 9)                wS[tid] = w[c0 * 9 + tid];
    else if (tid < CPB * 10)          wS[tid] = s[c0 + tid - CPB * 9];
    else if (tid < CPB * 11)          wS[tid] = b[c0 + tid - CPB * 10];

    // zero-fill padded planes (halo must be 0; interior overwritten below)
    for (int i = tid; i < CPB * 900; i += 256) ((float*)t)[i] = 0.f;
    __syncthreads();

    // stage: CPB*196 float4 tasks; each row of 28 = 7 aligned float4
    for (int idx = tid; idx < CPB * 196; idx += 256) {
        int ch  = idx / 196;
        int rm  = idx - ch * 196;
        int row = rm / 7, seg = rm - row * 7;
        float4 v = *(const float4*)&ip[ch * PP + row * 28 + seg * 4];
        float* dst = &t[ch][(row + 1) * 30 + seg * 4 + 1];
        dst[0] = v.x; dst[1] = v.y; dst[2] = v.z; dst[3] = v.w;
    }
    __syncthreads();

    // compute: 4-px segments; padded window rows row..row+2, cols x0..x0+5
    for (int idx = tid; idx < CPB * 196; idx += 256) {
        int ch  = idx / 196;
        int rm  = idx - ch * 196;
        int row = rm / 7, seg = rm - row * 7;
        int x0  = seg * 4;
        float w9[9];
#pragma unroll
        for (int i = 0; i < 9; i++) w9[i] = wS[ch * 9 + i];
        float sc = wS[CPB * 9 + ch], bb = wS[CPB * 10 + ch];

        float acc[4] = {0.f, 0.f, 0.f, 0.f};
        float ctr[4];
        const float* base = &t[ch][row * 30 + x0];
#pragma unroll
        for (int i = 0; i < 3; i++) {
            float r[6];
#pragma unroll
            for (int k = 0; k < 6; k++) r[k] = base[i * 30 + k];
            if (i == 1) { ctr[0] = r[1]; ctr[1] = r[2]; ctr[2] = r[3]; ctr[3] = r[4]; }
#pragma unroll
            for (int j = 0; j < 3; j++)
#pragma unroll
                for (int q = 0; q < 4; q++)
                    acc[q] += w9[i * 3 + j] * r[j + q];
        }
        float4 o;
        o.x = ctr[0] + acc[0] * sc + bb;
        o.y = ctr[1] + acc[1] * sc + bb;
        o.z = ctr[2] + acc[2] * sc + bb;
        o.w = ctr[3] + acc[3] * sc + bb;
        *(float4*)&op[ch * PP + row * 28 + x0] = o;
        *(float4*)&outL[ch][row * 28 + x0]     = o;
    }
    __syncthreads();

    // NHWC bf16 mirror: 784 px, 8B chunk (4 ch) each
    unsigned short* oBu = (unsigned short*)outB;
    for (int p = tid; p < PP; p += 256) {
        union { unsigned short h[4]; uint2 u; } pk;
#pragma unroll
        for (int ch = 0; ch < CPB; ch++) pk.h[ch] = f2bits(outL[ch][p]);
        *(uint2*)&oBu[((size_t)n * PP + p) * DIMC + c0] = pk.u;
    }
}

// ---------------------------------------------------------------------------
// Per-head depthwise 5x5 + BN on q channels — round-5 LDS version (proven).
// grid (NHH, BB), block 256, LDS 32 KB.
// ---------------------------------------------------------------------------
__global__ __launch_bounds__(256) void dws5x5_nhwc(
    const bf16* __restrict__ qkv,   // [64][784][384]
    const float* __restrict__ w,    // [64][25]  (hk-major)
    const float* __restrict__ s, const float* __restrict__ b,
    bf16* __restrict__ qout)        // [64][784][64]
{
    __shared__ __align__(16) unsigned short qin[32 * 32 * 16];  // [r][c][ch]
    int hh  = blockIdx.x;
    int n   = blockIdx.y;
    int tid = threadIdx.x;
    const unsigned short* KVu = (const unsigned short*)qkv;

    int kcw = tid & 15;
    int hk  = hh * 16 + kcw;
    float w25[25];
#pragma unroll
    for (int i = 0; i < 25; i++) w25[i] = w[hk * 25 + i];
    float csc = s[hk], cbb = b[hk];

    // zero-fill (halo must be 0), then stage interior
    for (int i = tid; i < 4096; i += 256)
        ((uint4*)qin)[i] = make_uint4(0u, 0u, 0u, 0u);
    __syncthreads();
    for (int idx = tid; idx < 1568; idx += 256) {
        int p = idx >> 1, half = idx & 1;
        int h = p / 28, x = p - h * 28;
        uint4 v = *(const uint4*)&KVu[((size_t)n * PP + p) * 384 + hh * 96 + half * 8];
        *(uint4*)&qin[((h + 2) * 32 + (x + 2)) * 16 + half * 8] = v;
    }
    __syncthreads();

    // compute: 784 px x 16 ch tasks
    for (int idx = tid; idx < 12544; idx += 256) {
        int p = idx >> 4;            // channel == kcw since 256 % 16 == 0
        int h = p / 28, x = p - h * 28;
        float acc = 0.f;
#pragma unroll
        for (int i = 0; i < 5; i++)
#pragma unroll
            for (int j = 0; j < 5; j++)
                acc += w25[i * 5 + j] * bits2f(qin[((h + i) * 32 + (x + j)) * 16 + kcw]);
        qout[((size_t)n * PP + p) * 64 + hk] = __float2bfloat16(acc * csc + cbb);
    }
}

// ---------------------------------------------------------------------------
// 1x1 conv as bf16 MFMA GEMM — round-7 gll staging + ROUND-8 XCD swizzle.
// Measured r7: FETCH 132 MB vs ~103 ideal — the 4 co-tiles sharing an X panel
// sat on different XCDs (IDs 7 apart, round-robin). Remap physical wid ->
// logical (n, p-tile, co-tile) with co-tile FASTEST and nwg/8 contiguous
// logical chunks per XCD (nwg%8==0 for all 6 dispatches; bijective).
// Tile 64(co) x 112(p), K-step 32, 4 waves. LDS 2 x 7 KB, 0 bank conflicts.
// OUTMODE: 0 = bf16 NHWC; 1 = fp32 NCHW; 2 = both.   grid (7, M/64, 64)
// ---------------------------------------------------------------------------
template <bool RELU, bool RES, int OUTMODE>
__global__ __launch_bounds__(256) void gemm_mfma(
    const bf16* __restrict__ Wb,    // [M][K] bf16
    const bf16* __restrict__ X,     // [64][784][K] bf16 NHWC
    const float* __restrict__ S, const float* __restrict__ Bb,
    const float* __restrict__ res,  // [64][M][784] fp32 NCHW (if RES)
    float* __restrict__ outF,       // fp32 NCHW (OUTMODE 1/2)
    bf16*  __restrict__ outB,       // bf16 NHWC (OUTMODE 0/2)
    int M, int K)
{
    // chunked-XCD bijective remap (nwg % 8 == 0 for all instantiations)
    int nwg = gridDim.x * gridDim.y * gridDim.z;
    int wid = (blockIdx.z * gridDim.y + blockIdx.y) * gridDim.x + blockIdx.x;
    int lin = (wid & 7) * (nwg >> 3) + (wid >> 3);
    int yb  = lin % gridDim.y;             // co-tile (fastest: shares X panel)
    int t2  = lin / gridDim.y;
    int xb  = t2 % gridDim.x;              // p-tile
    int n   = t2 / gridDim.x;              // image

    int co0  = yb * 64;
    int p0   = xb * 112;
    int tid  = threadIdx.x;
    int wv   = tid >> 6;
    int ln   = tid & 63;
    int l15  = ln & 15;
    int quad = ln >> 4;

    __shared__ __align__(16) unsigned short Blds[2][112 * 32];  // linear 64B rows

    floatx4 acc[7];
#pragma unroll
    for (int t = 0; t < 7; t++) acc[t] = (floatx4){0.f, 0.f, 0.f, 0.f};

    const bf16* Arow = Wb + (size_t)(co0 + wv * 16 + l15) * K + quad * 8;
    const unsigned short* Xb = (const unsigned short*)X + ((size_t)n * PP + p0) * K;

    // staging geometry: issue A covers rows 0..63 (all waves), issue B rows
    // 64..111 (waves 0..2). dest = wave-uniform LDS base + lane*16.
    int rA = wv * 16 + (ln >> 2);            // 0..63
    int rB = 64 + wv * 16 + (ln >> 2);       // 64..111 (wv<3)
    int cA = (ln & 3) ^ ((rA >> 1) & 3);     // pre-swizzled source chunk
    int cB = (ln & 3) ^ ((rB >> 1) & 3);
    const unsigned short* gA = Xb + (size_t)rA * K + cA * 8;
    const unsigned short* gB = Xb + (size_t)rB * K + cB * 8;

    // prologue: stage tile 0
    gll16(gA, &Blds[0][(wv * 16) * 32]);
    if (wv < 3) gll16(gB, &Blds[0][(64 + wv * 16) * 32]);
    short8 af = *(const short8*)Arow;
    __syncthreads();

    int NT = K >> 5;
    for (int t = 0; t < NT; t++) {
        int cur = t & 1;
        short8 naf = af;
        if (t + 1 < NT) {
            gll16(gA + (t + 1) * 32, &Blds[cur ^ 1][(wv * 16) * 32]);
            if (wv < 3) gll16(gB + (t + 1) * 32, &Blds[cur ^ 1][(64 + wv * 16) * 32]);
            naf = *(const short8*)(Arow + (t + 1) * 32);
        }
#pragma unroll
        for (int tt = 0; tt < 7; tt++) {
            int row = tt * 16 + l15;
            short8 bfrag = *(const short8*)
                &Blds[cur][row * 32 + ((quad ^ ((row >> 1) & 3)) * 8)];
            acc[tt] = __builtin_amdgcn_mfma_f32_16x16x32_bf16(af, bfrag, acc[tt], 0, 0, 0);
        }
        af = naf;
        __syncthreads();   // vmcnt(0) drain (stage done) + reads of buf[cur] done
    }

    int cobase = co0 + wv * 16 + quad * 4;
    float s4[4], b4[4];
#pragma unroll
    for (int r = 0; r < 4; r++) { s4[r] = S[cobase + r]; b4[r] = Bb[cobase + r]; }

#pragma unroll
    for (int t = 0; t < 7; t++) {
        int p = p0 + t * 16 + l15;   // always < 784
        float y[4];
#pragma unroll
        for (int r = 0; r < 4; r++) {
            y[r] = acc[t][r] * s4[r] + b4[r];
            if (RELU) y[r] = fmaxf(y[r], 0.f);
            if (RES) y[r] += res[((size_t)n * M + cobase + r) * PP + p];
        }
        if (OUTMODE == 1 || OUTMODE == 2) {
#pragma unroll
            for (int r = 0; r < 4; r++)
                outF[((size_t)n * M + cobase + r) * PP + p] = y[r];
        }
        if (OUTMODE == 0 || OUTMODE == 2) {
            union { unsigned short h4[4]; uint2 u; } pk;
#pragma unroll
            for (int r = 0; r < 4; r++) pk.h4[r] = f2bits(y[r]);
            *(uint2*)((unsigned short*)outB + ((size_t)n * PP + p) * M + cobase) = pk.u;
        }
    }
}

// ---------------------------------------------------------------------------
// 7x7 window attention — round-1 MFMA version (proven).
// grid (8, 4, 64), block 256.
// ---------------------------------------------------------------------------
__global__ __launch_bounds__(256) void attn_kernel(
    const bf16*  __restrict__ Q,       // [64][784][64] NHWC (hk = hh*16+kc)
    const bf16*  __restrict__ KV,      // [64][784][384] NHWC
    const float* __restrict__ pos,     // [4][49][49]
    bf16* __restrict__ O)              // [64][784][256] NHWC (c = hh*64+d)
{
    int wjp = blockIdx.x & 1, wi = blockIdx.x >> 1;
    int hh  = blockIdx.y, n = blockIdx.z;
    int tid = threadIdx.x;
    int pbase = wi * 7 * 28 + wjp * 14;

    __shared__ __align__(16) char smem[51712];
    unsigned short* qS = (unsigned short*)smem;              // [2][64][40]
    unsigned short* kS = qS + 2 * 64 * 40;                   // [2][64][40]
    unsigned short* pS = (unsigned short*)smem;              // alias: [2][64][72]
    unsigned short* vT = (unsigned short*)(smem + 20480);    // [2][64][72]
    float*          posL = (float*)(smem + 20480 + 18432);   // [64][50]

    const unsigned short* Qu  = (const unsigned short*)Q;
    const unsigned short* KVu = (const unsigned short*)KV;

    // ---- load q, k: 2 bufs x 2 windows x 64 rows x 5 halves (zero-padded) ----
    for (int idx = tid; idx < 1280; idx += 256) {
        int which = idx >= 640 ? 1 : 0;
        int t2 = idx - which * 640;
        int w = t2 / 320, rm = t2 - w * 320;
        int row = rm / 5, half = rm - row * 5;
        uint4 v = make_uint4(0u, 0u, 0u, 0u);
        if (row < 49 && half < 2) {
            int p = pbase + (row / 7) * 28 + w * 7 + (row % 7);
            const unsigned short* src = which
                ? &KVu[((size_t)n * PP + p) * 384 + hh * 96 + 16 + half * 8]
                : &Qu[((size_t)n * PP + p) * 64 + hh * 16 + half * 8];
            v = *(const uint4*)src;
        }
        *(uint4*)((which ? kS : qS) + (w * 64 + row) * 40 + half * 8) = v;
    }
    // ---- stage V transposed: vT[w][d][ki], zero cols for ki >= 49 ----
    for (int idx = tid; idx < 1024; idx += 256) {
        int w = idx >> 9, rm = idx & 511;
        int ki = rm >> 3, dq = rm & 7;
        union { uint4 q; unsigned short h[8]; } v;
        v.q = make_uint4(0u, 0u, 0u, 0u);
        if (ki < 49) {
            int p = pbase + (ki / 7) * 28 + w * 7 + (ki % 7);
            v.q = *(const uint4*)&KVu[((size_t)n * PP + p) * 384 + hh * 96 + 32 + dq * 8];
        }
#pragma unroll
        for (int j = 0; j < 8; j++)
            vT[(w * 64 + dq * 8 + j) * 72 + ki] = v.h[j];
    }
    // ---- stage pos [64][50], zero-padded ----
    for (int idx = tid; idx < 3200; idx += 256) {
        int r = idx / 50, c = idx - r * 50;
        posL[idx] = (r < 49 && c < 49) ? pos[((size_t)hh * 49 + r) * 49 + c] : 0.f;
    }
    __syncthreads();

    int wv = tid >> 6, ln = tid & 63, l15 = ln & 15, quad = ln >> 4;

    // ---- S^T via MFMA + in-register softmax; hold packed bf16 P ----
    uint2 pk[2][4];
#pragma unroll
    for (int w = 0; w < 2; w++) {
        short8 qf = *(const short8*)&qS[(w * 64 + wv * 16 + l15) * 40 + quad * 8];
        floatx4 a4[4];
#pragma unroll
        for (int kt = 0; kt < 4; kt++) {
            short8 kf = *(const short8*)&kS[(w * 64 + kt * 16 + l15) * 40 + quad * 8];
            a4[kt] = __builtin_amdgcn_mfma_f32_16x16x32_bf16(
                kf, qf, (floatx4){0.f, 0.f, 0.f, 0.f}, 0, 0, 0);
        }
        int q = wv * 16 + l15;
        float sv[16];
        float m = -1e30f;
#pragma unroll
        for (int kt = 0; kt < 4; kt++) {
#pragma unroll
            for (int r = 0; r < 4; r++) {
                int ki = kt * 16 + quad * 4 + r;
                float sc = (ki < 49)
                    ? a4[kt][r] * 0.25f + posL[q * 50 + ki]
                    : -1e30f;
                sv[kt * 4 + r] = sc;
                m = fmaxf(m, sc);
            }
        }
        m = fmaxf(m, __shfl_xor(m, 16));
        m = fmaxf(m, __shfl_xor(m, 32));
        float sum = 0.f;
#pragma unroll
        for (int i = 0; i < 16; i++) { sv[i] = __expf(sv[i] - m); sum += sv[i]; }
        sum += __shfl_xor(sum, 16);
        sum += __shfl_xor(sum, 32);
        float inv = 1.f / sum;
#pragma unroll
        for (int kt = 0; kt < 4; kt++) {
            union { uint2 u; unsigned short h[4]; } pku;
#pragma unroll
            for (int r = 0; r < 4; r++) pku.h[r] = f2bits(sv[kt * 4 + r] * inv);
            pk[w][kt] = pku.u;
        }
    }
    __syncthreads();   // all qS/kS MFMA reads done before aliasing writes

    {
        int q = wv * 16 + l15;
#pragma unroll
        for (int w = 0; w < 2; w++)
#pragma unroll
            for (int kt = 0; kt < 4; kt++)
                *(uint2*)&pS[(w * 64 + q) * 72 + kt * 16 + quad * 4] = pk[w][kt];
    }
    __syncthreads();

    // ---- O = relu(P @ V) via MFMA ----
    unsigned short* Ou = (unsigned short*)O;
#pragma unroll
    for (int w = 0; w < 2; w++) {
        short8 af0 = *(const short8*)&pS[(w * 64 + wv * 16 + l15) * 72 + quad * 8];
        short8 af1 = *(const short8*)&pS[(w * 64 + wv * 16 + l15) * 72 + 32 + quad * 8];
#pragma unroll
        for (int dt = 0; dt < 4; dt++) {
            floatx4 oacc = (floatx4){0.f, 0.f, 0.f, 0.f};
            short8 vf0 = *(const short8*)&vT[(w * 64 + dt * 16 + l15) * 72 + quad * 8];
            short8 vf1 = *(const short8*)&vT[(w * 64 + dt * 16 + l15) * 72 + 32 + quad * 8];
            oacc = __builtin_amdgcn_mfma_f32_16x16x32_bf16(af0, vf0, oacc, 0, 0, 0);
            oacc = __builtin_amdgcn_mfma_f32_16x16x32_bf16(af1, vf1, oacc, 0, 0, 0);
#pragma unroll
            for (int r = 0; r < 4; r++) {
                int q = wv * 16 + quad * 4 + r;
                if (q < 49) {
                    int p = pbase + (q / 7) * 28 + w * 7 + (q % 7);
                    Ou[((size_t)n * PP + p) * 256 + hh * 64 + dt * 16 + l15] =
                        f2bits(fmaxf(oacc[r], 0.f));
                }
            }
        }
    }
}

// ---------------------------------------------------------------------------
extern "C" void kernel_launch(void* const* d_in, const int* in_sizes, int n_in,
                              void* d_out, int out_size, void* d_ws, size_t ws_size,
                              hipStream_t stream)
{
    const float* x0     = (const float*)d_in[0];
    const float* dw0_w  = (const float*)d_in[1];
    const float* dw0_s  = (const float*)d_in[2];
    const float* dw0_b  = (const float*)d_in[3];
    const float* dw1_w  = (const float*)d_in[4];
    const float* dw1_s  = (const float*)d_in[5];
    const float* dw1_b  = (const float*)d_in[6];
    const float* f0w1   = (const float*)d_in[7];
    const float* f0s1   = (const float*)d_in[8];
    const float* f0b1   = (const float*)d_in[9];
    const float* f0w2   = (const float*)d_in[10];
    const float* f0s2   = (const float*)d_in[11];
    const float* f0b2   = (const float*)d_in[12];
    const float* f1w1   = (const float*)d_in[13];
    const float* f1s1   = (const float*)d_in[14];
    const float* f1b1   = (const float*)d_in[15];
    const float* f1w2   = (const float*)d_in[16];
    const float* f1s2   = (const float*)d_in[17];
    const float* f1b2   = (const float*)d_in[18];
    const float* qkv_w  = (const float*)d_in[19];
    const float* qkv_s  = (const float*)d_in[20];
    const float* qkv_b  = (const float*)d_in[21];
    const float* dws_w  = (const float*)d_in[22];
    const float* dws_s  = (const float*)d_in[23];
    const float* dws_b  = (const float*)d_in[24];
    const float* proj_w = (const float*)d_in[25];
    const float* proj_s = (const float*)d_in[26];
    const float* proj_b = (const float*)d_in[27];
    const float* pos    = (const float*)d_in[28];

    // -------- workspace (aliased, same proven scheme) --------
    const size_t NXB = (size_t)BB * DIMC * PP * 4;    // 51,380,224 B
    char* base  = (char*)d_ws;
    float* X1   = (float*)base;
    bf16*  Hb   = (bf16*)(base + NXB);
    bf16*  Qb   = Hb;                                  // alias, disjoint in time
    char*  C_   = base + 2 * NXB;
    bf16*  QKVb = (bf16*)C_;
    float* X2   = (float*)C_;                          // alias, disjoint in time
    bf16*  X1b  = (bf16*)(base + 3 * NXB);             // 25.7 MB
    bf16*  Wc   = (bf16*)(base + 3 * NXB + NXB / 2);
    bf16*  Ob   = (bf16*)d_out;
    float* outp = (float*)d_out;

    bf16* Wf0w1 = Wc;                  // [512][256]
    bf16* Wf0w2 = Wf0w1 + 131072;      // [256][512]
    bf16* Wf1w1 = Wf0w2 + 131072;      // [512][256]
    bf16* Wf1w2 = Wf1w1 + 131072;      // [256][512]
    bf16* Wqkv  = Wf1w2 + 131072;      // [384][256]
    bf16* Wproj = Wqkv + 98304;        // [256][256]

    dim3 blk(256);

    // 0) weights fp32 -> bf16 (single merged launch)
    cvt_all<<<2688, blk, 0, stream>>>(f0w1, Wf0w1, f0w2, Wf0w2,
                                      f1w1, Wf1w1, f1w2, Wf1w2,
                                      qkv_w, Wqkv, proj_w, Wproj);

    // 1) x = x + dw0(x); writes fp32 NCHW + bf16 NHWC mirror (tr_cvt deleted)
    dw3x3_kernel<<<dim3(DIMC / CPB, BB), blk, 0, stream>>>(
        x0, dw0_w, dw0_s, dw0_b, X1, X1b);

    // 2-3) ffn0 (second GEMM refreshes both X1 fp32 and X1b NHWC)
    gemm_mfma<true, false, 0><<<dim3(7, HIDC / 64, BB), blk, 0, stream>>>(
        Wf0w1, X1b, f0s1, f0b1, nullptr, nullptr, Hb, HIDC, DIMC);
    gemm_mfma<false, true, 2><<<dim3(7, DIMC / 64, BB), blk, 0, stream>>>(
        Wf0w2, Hb, f0s2, f0b2, X1, X1, X1b, DIMC, HIDC);

    // 4-7) attention
    gemm_mfma<false, false, 0><<<dim3(7, 384 / 64, BB), blk, 0, stream>>>(
        Wqkv, X1b, qkv_s, qkv_b, nullptr, nullptr, QKVb, 384, DIMC);
    dws5x5_nhwc<<<dim3(NHH, BB), blk, 0, stream>>>(QKVb, dws_w, dws_s, dws_b, Qb);
    attn_kernel<<<dim3(8, NHH, BB), blk, 0, stream>>>(Qb, QKVb, pos, Ob);
    gemm_mfma<false, true, 1><<<dim3(7, DIMC / 64, BB), blk, 0, stream>>>(
        Wproj, Ob, proj_s, proj_b, X1, X1, nullptr, DIMC, DIMC);

    // 8) x = x + dw1(x): fp32 NCHW X2 + bf16 NHWC mirror (QKVb dead -> X2)
    dw3x3_kernel<<<dim3(DIMC / CPB, BB), blk, 0, stream>>>(
        X1, dw1_w, dw1_s, dw1_b, X2, X1b);

    // 9-10) ffn1, final fp32 NCHW to d_out
    gemm_mfma<true, false, 0><<<dim3(7, HIDC / 64, BB), blk, 0, stream>>>(
        Wf1w1, X1b, f1s1, f1b1, nullptr, nullptr, Hb, HIDC, DIMC);
    gemm_mfma<false, true, 1><<<dim3(7, DIMC / 64, BB), blk, 0, stream>>>(
        Wf1w2, Hb, f1s2, f1b2, X2, outp, nullptr, DIMC, HIDC);
}

// Round 13
// 463.813 us; speedup vs baseline: 1.5607x; 1.0189x over previous
//
#include <hip/hip_runtime.h>
#include <hip/hip_bf16.h>
#include <math.h>

typedef __hip_bfloat16 bf16;
typedef __attribute__((ext_vector_type(8))) short short8;   // 8 x bf16 MFMA frag
typedef __attribute__((ext_vector_type(4))) float floatx4;  // 4 x f32 MFMA acc

// Problem constants: B=64, DIM=256, HID=512, NH=4, KD=16, D=64, 28x28, WH=7
#define BB    64
#define DIMC  256
#define HIDC  512
#define NHH   4
#define HH_   28
#define WW_   28
#define PP    784   // 28*28

__device__ __forceinline__ float toF(bf16 x) { return __bfloat162float(x); }
__device__ __forceinline__ unsigned short f2bits(float f) {
    union { bf16 h; unsigned short u; } cv; cv.h = __float2bfloat16(f); return cv.u;
}
__device__ __forceinline__ float bits2f(unsigned short u) {
    union { unsigned int u32; float f; } cv; cv.u32 = ((unsigned int)u) << 16; return cv.f;
}

// async 16B global -> LDS (wave-uniform LDS base + lane*16; vmcnt-counted)
__device__ __forceinline__ void gll16(const void* g, void* l) {
    __builtin_amdgcn_global_load_lds(
        (const __attribute__((address_space(1))) void*)g,
        (__attribute__((address_space(3))) void*)l, 16, 0, 0);
}

// ---------------------------------------------------------------------------
// fp32 -> bf16 weight convert — single merged launch for all 6 weight arrays
// ---------------------------------------------------------------------------
__global__ __launch_bounds__(256) void cvt_all(
    const float* __restrict__ s0, bf16* __restrict__ d0,   // 131072
    const float* __restrict__ s1, bf16* __restrict__ d1,   // 131072
    const float* __restrict__ s2, bf16* __restrict__ d2,   // 131072
    const float* __restrict__ s3, bf16* __restrict__ d3,   // 131072
    const float* __restrict__ s4, bf16* __restrict__ d4,   // 98304
    const float* __restrict__ s5, bf16* __restrict__ d5)   // 65536
{
    int i = blockIdx.x * 256 + threadIdx.x;
    if (i < 131072)                d0[i]          = __float2bfloat16(s0[i]);
    else if (i < 262144)           d1[i - 131072] = __float2bfloat16(s1[i - 131072]);
    else if (i < 393216)           d2[i - 262144] = __float2bfloat16(s2[i - 262144]);
    else if (i < 524288)           d3[i - 393216] = __float2bfloat16(s3[i - 393216]);
    else if (i < 622592)           d4[i - 524288] = __float2bfloat16(s4[i - 524288]);
    else if (i < 688128)           d5[i - 622592] = __float2bfloat16(s5[i - 622592]);
}

// ---------------------------------------------------------------------------
// Depthwise 3x3 conv + BN + residual + bf16 NHWC mirror — ROUND-11 (resubmit;
// round-12 bench was an infra timeout, no signal).
// Register shfl transpose, halo-only zero (strided loop over 464 cells —
// round-10's `if (tid < 464)` bug fixed), 14.4 KB LDS, one barrier.
// grid (64 cgroups, BB) with chunked-XCD remap, block 256.
// ---------------------------------------------------------------------------
#define CPB 4
__global__ __launch_bounds__(256) void dw3x3_kernel(
    const float* __restrict__ in, const float* __restrict__ w,
    const float* __restrict__ s, const float* __restrict__ b,
    float* __restrict__ out, bf16* __restrict__ outB)
{
    __shared__ float t[CPB][30 * 30];        // padded planes, zero halo

    // chunked-XCD bijective remap: one image's 64 cgroups contiguous per XCD
    int wid = blockIdx.y * gridDim.x + blockIdx.x;         // 0..4095
    int lin = (wid & 7) * 512 + (wid >> 3);                // 4096/8 = 512
    int cg  = lin & 63;
    int n   = lin >> 6;
    int c0  = cg * CPB;

    int tid = threadIdx.x;
    int lm  = tid & 3;                       // this thread's channel (c0+lm)
    const float* ip = in  + ((size_t)n * DIMC + c0) * PP;
    float*       op = out + ((size_t)n * DIMC + c0) * PP;

    // per-thread channel weights (global scalar loads, L1/L2-cached)
    float w9[9];
#pragma unroll
    for (int i = 0; i < 9; i++) w9[i] = w[(c0 + lm) * 9 + i];
    float sc = s[c0 + lm], bb = b[c0 + lm];

    // zero HALO cells only (116/plane x 4 = 464) — strided over the block
    for (int i = tid; i < 464; i += 256) {
        int plane = i / 116, bq = i - plane * 116;
        int cell;
        if (bq < 30)       cell = bq;                       // top row
        else if (bq < 60)  cell = 870 + (bq - 30);          // bottom row
        else if (bq < 88)  cell = (bq - 60 + 1) * 30;       // left col r=1..28
        else               cell = (bq - 88 + 1) * 30 + 29;  // right col
        t[plane][cell] = 0.f;
    }
    // stage interior: 784 float4 tasks (ch-major for coalescing)
    for (int idx = tid; idx < CPB * 196; idx += 256) {
        int ch  = idx / 196;
        int rm  = idx - ch * 196;
        int row = rm / 7, seg = rm - row * 7;
        float4 v = *(const float4*)&ip[ch * PP + row * 28 + seg * 4];
        float* dst = &t[ch][(row + 1) * 30 + seg * 4 + 1];
        dst[0] = v.x; dst[1] = v.y; dst[2] = v.z; dst[3] = v.w;
    }
    __syncthreads();

    // compute: px-major tasks; idx&3 == lm (256 % 4 == 0)
    unsigned short* oBu = (unsigned short*)outB;
    for (int idx = tid; idx < CPB * 196; idx += 256) {
        int rm  = idx >> 2;
        int row = rm / 7, seg = rm - row * 7;
        int x0  = seg * 4;

        float acc[4] = {0.f, 0.f, 0.f, 0.f};
        float ctr[4];
        const float* base = &t[lm][row * 30 + x0];
#pragma unroll
        for (int i = 0; i < 3; i++) {
            float r[6];
#pragma unroll
            for (int k = 0; k < 6; k++) r[k] = base[i * 30 + k];
            if (i == 1) { ctr[0] = r[1]; ctr[1] = r[2]; ctr[2] = r[3]; ctr[3] = r[4]; }
#pragma unroll
            for (int j = 0; j < 3; j++)
#pragma unroll
                for (int q = 0; q < 4; q++)
                    acc[q] += w9[i * 3 + j] * r[j + q];
        }
        float v0 = ctr[0] + acc[0] * sc + bb;
        float v1 = ctr[1] + acc[1] * sc + bb;
        float v2 = ctr[2] + acc[2] * sc + bb;
        float v3 = ctr[3] + acc[3] * sc + bb;

        // NCHW write (px-major layout is already right for this)
        float4 o; o.x = v0; o.y = v1; o.z = v2; o.w = v3;
        *(float4*)&op[lm * PP + row * 28 + x0] = o;

        // 4x4 transpose across the 4-lane group (static indices only):
        // step 1 (xor 2): swap off-diagonal 2x2 blocks
        float ea = __shfl_xor((lm & 2) ? v0 : v2, 2);
        float eb = __shfl_xor((lm & 2) ? v1 : v3, 2);
        v0 = (lm & 2) ? ea : v0;  v1 = (lm & 2) ? eb : v1;
        v2 = (lm & 2) ? v2 : ea;  v3 = (lm & 2) ? v3 : eb;
        // step 2 (xor 1): transpose within 2x2 blocks
        float ec = __shfl_xor((lm & 1) ? v0 : v1, 1);
        float ed = __shfl_xor((lm & 1) ? v2 : v3, 1);
        v0 = (lm & 1) ? ec : v0;  v1 = (lm & 1) ? v1 : ec;
        v2 = (lm & 1) ? ed : v2;  v3 = (lm & 1) ? v3 : ed;
        // lane q holds channels c0..c0+3 of pixel row*28 + x0 + q
        int p = row * 28 + x0 + lm;
        union { unsigned short h[4]; uint2 u; } pk;
        pk.h[0] = f2bits(v0); pk.h[1] = f2bits(v1);
        pk.h[2] = f2bits(v2); pk.h[3] = f2bits(v3);
        *(uint2*)&oBu[((size_t)n * PP + p) * DIMC + c0] = pk.u;
    }
}

// ---------------------------------------------------------------------------
// Per-head depthwise 5x5 + BN on q channels — round-5 LDS version (proven).
// grid (NHH, BB), block 256, LDS 32 KB.
// ---------------------------------------------------------------------------
__global__ __launch_bounds__(256) void dws5x5_nhwc(
    const bf16* __restrict__ qkv,   // [64][784][384]
    const float* __restrict__ w,    // [64][25]  (hk-major)
    const float* __restrict__ s, const float* __restrict__ b,
    bf16* __restrict__ qout)        // [64][784][64]
{
    __shared__ __align__(16) unsigned short qin[32 * 32 * 16];  // [r][c][ch]
    int hh  = blockIdx.x;
    int n   = blockIdx.y;
    int tid = threadIdx.x;
    const unsigned short* KVu = (const unsigned short*)qkv;

    int kcw = tid & 15;
    int hk  = hh * 16 + kcw;
    float w25[25];
#pragma unroll
    for (int i = 0; i < 25; i++) w25[i] = w[hk * 25 + i];
    float csc = s[hk], cbb = b[hk];

    // zero-fill (halo must be 0), then stage interior
    for (int i = tid; i < 4096; i += 256)
        ((uint4*)qin)[i] = make_uint4(0u, 0u, 0u, 0u);
    __syncthreads();
    for (int idx = tid; idx < 1568; idx += 256) {
        int p = idx >> 1, half = idx & 1;
        int h = p / 28, x = p - h * 28;
        uint4 v = *(const uint4*)&KVu[((size_t)n * PP + p) * 384 + hh * 96 + half * 8];
        *(uint4*)&qin[((h + 2) * 32 + (x + 2)) * 16 + half * 8] = v;
    }
    __syncthreads();

    // compute: 784 px x 16 ch tasks
    for (int idx = tid; idx < 12544; idx += 256) {
        int p = idx >> 4;            // channel == kcw since 256 % 16 == 0
        int h = p / 28, x = p - h * 28;
        float acc = 0.f;
#pragma unroll
        for (int i = 0; i < 5; i++)
#pragma unroll
            for (int j = 0; j < 5; j++)
                acc += w25[i * 5 + j] * bits2f(qin[((h + i) * 32 + (x + j)) * 16 + kcw]);
        qout[((size_t)n * PP + p) * 64 + hk] = __float2bfloat16(acc * csc + cbb);
    }
}

// ---------------------------------------------------------------------------
// 1x1 conv as bf16 MFMA GEMM — round-7 gll staging + round-8 XCD swizzle
// (proven: FETCH cut, total 554 -> 472.6). Tile 64(co) x 112(p), K-step 32,
// 4 waves, LDS 2 x 7 KB, 0 bank conflicts.
// OUTMODE: 0 = bf16 NHWC; 1 = fp32 NCHW; 2 = both.   grid (7, M/64, 64)
// ---------------------------------------------------------------------------
template <bool RELU, bool RES, int OUTMODE>
__global__ __launch_bounds__(256) void gemm_mfma(
    const bf16* __restrict__ Wb,    // [M][K] bf16
    const bf16* __restrict__ X,     // [64][784][K] bf16 NHWC
    const float* __restrict__ S, const float* __restrict__ Bb,
    const float* __restrict__ res,  // [64][M][784] fp32 NCHW (if RES)
    float* __restrict__ outF,       // fp32 NCHW (OUTMODE 1/2)
    bf16*  __restrict__ outB,       // bf16 NHWC (OUTMODE 0/2)
    int M, int K)
{
    // chunked-XCD bijective remap (nwg % 8 == 0 for all instantiations)
    int nwg = gridDim.x * gridDim.y * gridDim.z;
    int wid = (blockIdx.z * gridDim.y + blockIdx.y) * gridDim.x + blockIdx.x;
    int lin = (wid & 7) * (nwg >> 3) + (wid >> 3);
    int yb  = lin % gridDim.y;             // co-tile (fastest: shares X panel)
    int t2  = lin / gridDim.y;
    int xb  = t2 % gridDim.x;              // p-tile
    int n   = t2 / gridDim.x;              // image

    int co0  = yb * 64;
    int p0   = xb * 112;
    int tid  = threadIdx.x;
    int wv   = tid >> 6;
    int ln   = tid & 63;
    int l15  = ln & 15;
    int quad = ln >> 4;

    __shared__ __align__(16) unsigned short Blds[2][112 * 32];  // linear 64B rows

    floatx4 acc[7];
#pragma unroll
    for (int t = 0; t < 7; t++) acc[t] = (floatx4){0.f, 0.f, 0.f, 0.f};

    const bf16* Arow = Wb + (size_t)(co0 + wv * 16 + l15) * K + quad * 8;
    const unsigned short* Xb = (const unsigned short*)X + ((size_t)n * PP + p0) * K;

    // staging geometry: issue A covers rows 0..63 (all waves), issue B rows
    // 64..111 (waves 0..2). dest = wave-uniform LDS base + lane*16.
    int rA = wv * 16 + (ln >> 2);            // 0..63
    int rB = 64 + wv * 16 + (ln >> 2);       // 64..111 (wv<3)
    int cA = (ln & 3) ^ ((rA >> 1) & 3);     // pre-swizzled source chunk
    int cB = (ln & 3) ^ ((rB >> 1) & 3);
    const unsigned short* gA = Xb + (size_t)rA * K + cA * 8;
    const unsigned short* gB = Xb + (size_t)rB * K + cB * 8;

    // prologue: stage tile 0
    gll16(gA, &Blds[0][(wv * 16) * 32]);
    if (wv < 3) gll16(gB, &Blds[0][(64 + wv * 16) * 32]);
    short8 af = *(const short8*)Arow;
    __syncthreads();

    int NT = K >> 5;
    for (int t = 0; t < NT; t++) {
        int cur = t & 1;
        short8 naf = af;
        if (t + 1 < NT) {
            gll16(gA + (t + 1) * 32, &Blds[cur ^ 1][(wv * 16) * 32]);
            if (wv < 3) gll16(gB + (t + 1) * 32, &Blds[cur ^ 1][(64 + wv * 16) * 32]);
            naf = *(const short8*)(Arow + (t + 1) * 32);
        }
#pragma unroll
        for (int tt = 0; tt < 7; tt++) {
            int row = tt * 16 + l15;
            short8 bfrag = *(const short8*)
                &Blds[cur][row * 32 + ((quad ^ ((row >> 1) & 3)) * 8)];
            acc[tt] = __builtin_amdgcn_mfma_f32_16x16x32_bf16(af, bfrag, acc[tt], 0, 0, 0);
        }
        af = naf;
        __syncthreads();   // vmcnt(0) drain (stage done) + reads of buf[cur] done
    }

    int cobase = co0 + wv * 16 + quad * 4;
    float s4[4], b4[4];
#pragma unroll
    for (int r = 0; r < 4; r++) { s4[r] = S[cobase + r]; b4[r] = Bb[cobase + r]; }

#pragma unroll
    for (int t = 0; t < 7; t++) {
        int p = p0 + t * 16 + l15;   // always < 784
        float y[4];
#pragma unroll
        for (int r = 0; r < 4; r++) {
            y[r] = acc[t][r] * s4[r] + b4[r];
            if (RELU) y[r] = fmaxf(y[r], 0.f);
            if (RES) y[r] += res[((size_t)n * M + cobase + r) * PP + p];
        }
        if (OUTMODE == 1 || OUTMODE == 2) {
#pragma unroll
            for (int r = 0; r < 4; r++)
                outF[((size_t)n * M + cobase + r) * PP + p] = y[r];
        }
        if (OUTMODE == 0 || OUTMODE == 2) {
            union { unsigned short h4[4]; uint2 u; } pk;
#pragma unroll
            for (int r = 0; r < 4; r++) pk.h4[r] = f2bits(y[r]);
            *(uint2*)((unsigned short*)outB + ((size_t)n * PP + p) * M + cobase) = pk.u;
        }
    }
}

// ---------------------------------------------------------------------------
// 7x7 window attention — round-1 MFMA version (proven).
// grid (8, 4, 64), block 256.
// ---------------------------------------------------------------------------
__global__ __launch_bounds__(256) void attn_kernel(
    const bf16*  __restrict__ Q,       // [64][784][64] NHWC (hk = hh*16+kc)
    const bf16*  __restrict__ KV,      // [64][784][384] NHWC
    const float* __restrict__ pos,     // [4][49][49]
    bf16* __restrict__ O)              // [64][784][256] NHWC (c = hh*64+d)
{
    int wjp = blockIdx.x & 1, wi = blockIdx.x >> 1;
    int hh  = blockIdx.y, n = blockIdx.z;
    int tid = threadIdx.x;
    int pbase = wi * 7 * 28 + wjp * 14;

    __shared__ __align__(16) char smem[51712];
    unsigned short* qS = (unsigned short*)smem;              // [2][64][40]
    unsigned short* kS = qS + 2 * 64 * 40;                   // [2][64][40]
    unsigned short* pS = (unsigned short*)smem;              // alias: [2][64][72]
    unsigned short* vT = (unsigned short*)(smem + 20480);    // [2][64][72]
    float*          posL = (float*)(smem + 20480 + 18432);   // [64][50]

    const unsigned short* Qu  = (const unsigned short*)Q;
    const unsigned short* KVu = (const unsigned short*)KV;

    // ---- load q, k: 2 bufs x 2 windows x 64 rows x 5 halves (zero-padded) ----
    for (int idx = tid; idx < 1280; idx += 256) {
        int which = idx >= 640 ? 1 : 0;
        int t2 = idx - which * 640;
        int w = t2 / 320, rm = t2 - w * 320;
        int row = rm / 5, half = rm - row * 5;
        uint4 v = make_uint4(0u, 0u, 0u, 0u);
        if (row < 49 && half < 2) {
            int p = pbase + (row / 7) * 28 + w * 7 + (row % 7);
            const unsigned short* src = which
                ? &KVu[((size_t)n * PP + p) * 384 + hh * 96 + 16 + half * 8]
                : &Qu[((size_t)n * PP + p) * 64 + hh * 16 + half * 8];
            v = *(const uint4*)src;
        }
        *(uint4*)((which ? kS : qS) + (w * 64 + row) * 40 + half * 8) = v;
    }
    // ---- stage V transposed: vT[w][d][ki], zero cols for ki >= 49 ----
    for (int idx = tid; idx < 1024; idx += 256) {
        int w = idx >> 9, rm = idx & 511;
        int ki = rm >> 3, dq = rm & 7;
        union { uint4 q; unsigned short h[8]; } v;
        v.q = make_uint4(0u, 0u, 0u, 0u);
        if (ki < 49) {
            int p = pbase + (ki / 7) * 28 + w * 7 + (ki % 7);
            v.q = *(const uint4*)&KVu[((size_t)n * PP + p) * 384 + hh * 96 + 32 + dq * 8];
        }
#pragma unroll
        for (int j = 0; j < 8; j++)
            vT[(w * 64 + dq * 8 + j) * 72 + ki] = v.h[j];
    }
    // ---- stage pos [64][50], zero-padded ----
    for (int idx = tid; idx < 3200; idx += 256) {
        int r = idx / 50, c = idx - r * 50;
        posL[idx] = (r < 49 && c < 49) ? pos[((size_t)hh * 49 + r) * 49 + c] : 0.f;
    }
    __syncthreads();

    int wv = tid >> 6, ln = tid & 63, l15 = ln & 15, quad = ln >> 4;

    // ---- S^T via MFMA + in-register softmax; hold packed bf16 P ----
    uint2 pk[2][4];
#pragma unroll
    for (int w = 0; w < 2; w++) {
        short8 qf = *(const short8*)&qS[(w * 64 + wv * 16 + l15) * 40 + quad * 8];
        floatx4 a4[4];
#pragma unroll
        for (int kt = 0; kt < 4; kt++) {
            short8 kf = *(const short8*)&kS[(w * 64 + kt * 16 + l15) * 40 + quad * 8];
            a4[kt] = __builtin_amdgcn_mfma_f32_16x16x32_bf16(
                kf, qf, (floatx4){0.f, 0.f, 0.f, 0.f}, 0, 0, 0);
        }
        int q = wv * 16 + l15;
        float sv[16];
        float m = -1e30f;
#pragma unroll
        for (int kt = 0; kt < 4; kt++) {
#pragma unroll
            for (int r = 0; r < 4; r++) {
                int ki = kt * 16 + quad * 4 + r;
                float sc = (ki < 49)
                    ? a4[kt][r] * 0.25f + posL[q * 50 + ki]
                    : -1e30f;
                sv[kt * 4 + r] = sc;
                m = fmaxf(m, sc);
            }
        }
        m = fmaxf(m, __shfl_xor(m, 16));
        m = fmaxf(m, __shfl_xor(m, 32));
        float sum = 0.f;
#pragma unroll
        for (int i = 0; i < 16; i++) { sv[i] = __expf(sv[i] - m); sum += sv[i]; }
        sum += __shfl_xor(sum, 16);
        sum += __shfl_xor(sum, 32);
        float inv = 1.f / sum;
#pragma unroll
        for (int kt = 0; kt < 4; kt++) {
            union { uint2 u; unsigned short h[4]; } pku;
#pragma unroll
            for (int r = 0; r < 4; r++) pku.h[r] = f2bits(sv[kt * 4 + r] * inv);
            pk[w][kt] = pku.u;
        }
    }
    __syncthreads();   // all qS/kS MFMA reads done before aliasing writes

    {
        int q = wv * 16 + l15;
#pragma unroll
        for (int w = 0; w < 2; w++)
#pragma unroll
            for (int kt = 0; kt < 4; kt++)
                *(uint2*)&pS[(w * 64 + q) * 72 + kt * 16 + quad * 4] = pk[w][kt];
    }
    __syncthreads();

    // ---- O = relu(P @ V) via MFMA ----
    unsigned short* Ou = (unsigned short*)O;
#pragma unroll
    for (int w = 0; w < 2; w++) {
        short8 af0 = *(const short8*)&pS[(w * 64 + wv * 16 + l15) * 72 + quad * 8];
        short8 af1 = *(const short8*)&pS[(w * 64 + wv * 16 + l15) * 72 + 32 + quad * 8];
#pragma unroll
        for (int dt = 0; dt < 4; dt++) {
            floatx4 oacc = (floatx4){0.f, 0.f, 0.f, 0.f};
            short8 vf0 = *(const short8*)&vT[(w * 64 + dt * 16 + l15) * 72 + quad * 8];
            short8 vf1 = *(const short8*)&vT[(w * 64 + dt * 16 + l15) * 72 + 32 + quad * 8];
            oacc = __builtin_amdgcn_mfma_f32_16x16x32_bf16(af0, vf0, oacc, 0, 0, 0);
            oacc = __builtin_amdgcn_mfma_f32_16x16x32_bf16(af1, vf1, oacc, 0, 0, 0);
#pragma unroll
            for (int r = 0; r < 4; r++) {
                int q = wv * 16 + quad * 4 + r;
                if (q < 49) {
                    int p = pbase + (q / 7) * 28 + w * 7 + (q % 7);
                    Ou[((size_t)n * PP + p) * 256 + hh * 64 + dt * 16 + l15] =
                        f2bits(fmaxf(oacc[r], 0.f));
                }
            }
        }
    }
}

// ---------------------------------------------------------------------------
extern "C" void kernel_launch(void* const* d_in, const int* in_sizes, int n_in,
                              void* d_out, int out_size, void* d_ws, size_t ws_size,
                              hipStream_t stream)
{
    const float* x0     = (const float*)d_in[0];
    const float* dw0_w  = (const float*)d_in[1];
    const float* dw0_s  = (const float*)d_in[2];
    const float* dw0_b  = (const float*)d_in[3];
    const float* dw1_w  = (const float*)d_in[4];
    const float* dw1_s  = (const float*)d_in[5];
    const float* dw1_b  = (const float*)d_in[6];
    const float* f0w1   = (const float*)d_in[7];
    const float* f0s1   = (const float*)d_in[8];
    const float* f0b1   = (const float*)d_in[9];
    const float* f0w2   = (const float*)d_in[10];
    const float* f0s2   = (const float*)d_in[11];
    const float* f0b2   = (const float*)d_in[12];
    const float* f1w1   = (const float*)d_in[13];
    const float* f1s1   = (const float*)d_in[14];
    const float* f1b1   = (const float*)d_in[15];
    const float* f1w2   = (const float*)d_in[16];
    const float* f1s2   = (const float*)d_in[17];
    const float* f1b2   = (const float*)d_in[18];
    const float* qkv_w  = (const float*)d_in[19];
    const float* qkv_s  = (const float*)d_in[20];
    const float* qkv_b  = (const float*)d_in[21];
    const float* dws_w  = (const float*)d_in[22];
    const float* dws_s  = (const float*)d_in[23];
    const float* dws_b  = (const float*)d_in[24];
    const float* proj_w = (const float*)d_in[25];
    const float* proj_s = (const float*)d_in[26];
    const float* proj_b = (const float*)d_in[27];
    const float* pos    = (const float*)d_in[28];

    // -------- workspace (aliased, same proven scheme) --------
    const size_t NXB = (size_t)BB * DIMC * PP * 4;    // 51,380,224 B
    char* base  = (char*)d_ws;
    float* X1   = (float*)base;
    bf16*  Hb   = (bf16*)(base + NXB);
    bf16*  Qb   = Hb;                                  // alias, disjoint in time
    char*  C_   = base + 2 * NXB;
    bf16*  QKVb = (bf16*)C_;
    float* X2   = (float*)C_;                          // alias, disjoint in time
    bf16*  X1b  = (bf16*)(base + 3 * NXB);             // 25.7 MB
    bf16*  Wc   = (bf16*)(base + 3 * NXB + NXB / 2);
    bf16*  Ob   = (bf16*)d_out;
    float* outp = (float*)d_out;

    bf16* Wf0w1 = Wc;                  // [512][256]
    bf16* Wf0w2 = Wf0w1 + 131072;      // [256][512]
    bf16* Wf1w1 = Wf0w2 + 131072;      // [512][256]
    bf16* Wf1w2 = Wf1w1 + 131072;      // [256][512]
    bf16* Wqkv  = Wf1w2 + 131072;      // [384][256]
    bf16* Wproj = Wqkv + 98304;        // [256][256]

    dim3 blk(256);

    // 0) weights fp32 -> bf16 (single merged launch)
    cvt_all<<<2688, blk, 0, stream>>>(f0w1, Wf0w1, f0w2, Wf0w2,
                                      f1w1, Wf1w1, f1w2, Wf1w2,
                                      qkv_w, Wqkv, proj_w, Wproj);

    // 1) x = x + dw0(x); writes fp32 NCHW + bf16 NHWC mirror
    dw3x3_kernel<<<dim3(DIMC / CPB, BB), blk, 0, stream>>>(
        x0, dw0_w, dw0_s, dw0_b, X1, X1b);

    // 2-3) ffn0 (second GEMM refreshes both X1 fp32 and X1b NHWC)
    gemm_mfma<true, false, 0><<<dim3(7, HIDC / 64, BB), blk, 0, stream>>>(
        Wf0w1, X1b, f0s1, f0b1, nullptr, nullptr, Hb, HIDC, DIMC);
    gemm_mfma<false, true, 2><<<dim3(7, DIMC / 64, BB), blk, 0, stream>>>(
        Wf0w2, Hb, f0s2, f0b2, X1, X1, X1b, DIMC, HIDC);

    // 4-7) attention
    gemm_mfma<false, false, 0><<<dim3(7, 384 / 64, BB), blk, 0, stream>>>(
        Wqkv, X1b, qkv_s, qkv_b, nullptr, nullptr, QKVb, 384, DIMC);
    dws5x5_nhwc<<<dim3(NHH, BB), blk, 0, stream>>>(QKVb, dws_w, dws_s, dws_b, Qb);
    attn_kernel<<<dim3(8, NHH, BB), blk, 0, stream>>>(Qb, QKVb, pos, Ob);
    gemm_mfma<false, true, 1><<<dim3(7, DIMC / 64, BB), blk, 0, stream>>>(
        Wproj, Ob, proj_s, proj_b, X1, X1, nullptr, DIMC, DIMC);

    // 8) x = x + dw1(x): fp32 NCHW X2 + bf16 NHWC mirror (QKVb dead -> X2)
    dw3x3_kernel<<<dim3(DIMC / CPB, BB), blk, 0, stream>>>(
        X1, dw1_w, dw1_s, dw1_b, X2, X1b);

    // 9-10) ffn1, final fp32 NCHW to d_out
    gemm_mfma<true, false, 0><<<dim3(7, HIDC / 64, BB), blk, 0, stream>>>(
        Wf1w1, X1b, f1s1, f1b1, nullptr, nullptr, Hb, HIDC, DIMC);
    gemm_mfma<false, true, 1><<<dim3(7, DIMC / 64, BB), blk, 0, stream>>>(
        Wf1w2, Hb, f1s2, f1b2, X2, outp, nullptr, DIMC, HIDC);
}

// Round 15
// 446.111 us; speedup vs baseline: 1.6226x; 1.0397x over previous
//
#include <hip/hip_runtime.h>
#include <hip/hip_bf16.h>
#include <math.h>

typedef __hip_bfloat16 bf16;
typedef __attribute__((ext_vector_type(8))) short short8;   // 8 x bf16 MFMA frag
typedef __attribute__((ext_vector_type(4))) float floatx4;  // 4 x f32 MFMA acc

// Problem constants: B=64, DIM=256, HID=512, NH=4, KD=16, D=64, 28x28, WH=7
#define BB    64
#define DIMC  256
#define HIDC  512
#define NHH   4
#define HH_   28
#define WW_   28
#define PP    784   // 28*28

__device__ __forceinline__ float toF(bf16 x) { return __bfloat162float(x); }
__device__ __forceinline__ unsigned short f2bits(float f) {
    union { bf16 h; unsigned short u; } cv; cv.h = __float2bfloat16(f); return cv.u;
}
__device__ __forceinline__ float bits2f(unsigned short u) {
    union { unsigned int u32; float f; } cv; cv.u32 = ((unsigned int)u) << 16; return cv.f;
}

// async 16B global -> LDS (wave-uniform LDS base + lane*16; vmcnt-counted)
__device__ __forceinline__ void gll16(const void* g, void* l) {
    __builtin_amdgcn_global_load_lds(
        (const __attribute__((address_space(1))) void*)g,
        (__attribute__((address_space(3))) void*)l, 16, 0, 0);
}

// ---------------------------------------------------------------------------
// fp32 -> bf16 weight convert — single merged launch for all 6 weight arrays
// ---------------------------------------------------------------------------
__global__ __launch_bounds__(256) void cvt_all(
    const float* __restrict__ s0, bf16* __restrict__ d0,   // 131072
    const float* __restrict__ s1, bf16* __restrict__ d1,   // 131072
    const float* __restrict__ s2, bf16* __restrict__ d2,   // 131072
    const float* __restrict__ s3, bf16* __restrict__ d3,   // 131072
    const float* __restrict__ s4, bf16* __restrict__ d4,   // 98304
    const float* __restrict__ s5, bf16* __restrict__ d5)   // 65536
{
    int i = blockIdx.x * 256 + threadIdx.x;
    if (i < 131072)                d0[i]          = __float2bfloat16(s0[i]);
    else if (i < 262144)           d1[i - 131072] = __float2bfloat16(s1[i - 131072]);
    else if (i < 393216)           d2[i - 262144] = __float2bfloat16(s2[i - 262144]);
    else if (i < 524288)           d3[i - 393216] = __float2bfloat16(s3[i - 393216]);
    else if (i < 622592)           d4[i - 524288] = __float2bfloat16(s4[i - 524288]);
    else if (i < 688128)           d5[i - 622592] = __float2bfloat16(s5[i - 622592]);
}

// ---------------------------------------------------------------------------
// Depthwise 3x3 conv + BN + residual — round-13: dead fp32-NCHW write removed
// (WF=false). Register shfl transpose for the NHWC pack; halo-only zero
// (strided, r11 fix); 14.4 KB LDS, 1 barrier.
// grid (64 cgroups, BB) with chunked-XCD remap, block 256.
// ---------------------------------------------------------------------------
#define CPB 4
template <bool WF>
__global__ __launch_bounds__(256) void dw3x3_kernel(
    const float* __restrict__ in, const float* __restrict__ w,
    const float* __restrict__ s, const float* __restrict__ b,
    float* __restrict__ out, bf16* __restrict__ outB)
{
    __shared__ float t[CPB][30 * 30];        // padded planes, zero halo

    // chunked-XCD bijective remap: one image's 64 cgroups contiguous per XCD
    int wid = blockIdx.y * gridDim.x + blockIdx.x;         // 0..4095
    int lin = (wid & 7) * 512 + (wid >> 3);                // 4096/8 = 512
    int cg  = lin & 63;
    int n   = lin >> 6;
    int c0  = cg * CPB;

    int tid = threadIdx.x;
    int lm  = tid & 3;                       // this thread's channel (c0+lm)
    const float* ip = in  + ((size_t)n * DIMC + c0) * PP;
    float*       op = out + ((size_t)n * DIMC + c0) * PP;

    // per-thread channel weights (global scalar loads, L1/L2-cached)
    float w9[9];
#pragma unroll
    for (int i = 0; i < 9; i++) w9[i] = w[(c0 + lm) * 9 + i];
    float sc = s[c0 + lm], bb = b[c0 + lm];

    // zero HALO cells only (116/plane x 4 = 464) — strided over the block
    for (int i = tid; i < 464; i += 256) {
        int plane = i / 116, bq = i - plane * 116;
        int cell;
        if (bq < 30)       cell = bq;                       // top row
        else if (bq < 60)  cell = 870 + (bq - 30);          // bottom row
        else if (bq < 88)  cell = (bq - 60 + 1) * 30;       // left col r=1..28
        else               cell = (bq - 88 + 1) * 30 + 29;  // right col
        t[plane][cell] = 0.f;
    }
    // stage interior: 784 float4 tasks (ch-major for coalescing)
    for (int idx = tid; idx < CPB * 196; idx += 256) {
        int ch  = idx / 196;
        int rm  = idx - ch * 196;
        int row = rm / 7, seg = rm - row * 7;
        float4 v = *(const float4*)&ip[ch * PP + row * 28 + seg * 4];
        float* dst = &t[ch][(row + 1) * 30 + seg * 4 + 1];
        dst[0] = v.x; dst[1] = v.y; dst[2] = v.z; dst[3] = v.w;
    }
    __syncthreads();

    // compute: px-major tasks; idx&3 == lm (256 % 4 == 0)
    unsigned short* oBu = (unsigned short*)outB;
    for (int idx = tid; idx < CPB * 196; idx += 256) {
        int rm  = idx >> 2;
        int row = rm / 7, seg = rm - row * 7;
        int x0  = seg * 4;

        float acc[4] = {0.f, 0.f, 0.f, 0.f};
        float ctr[4];
        const float* base = &t[lm][row * 30 + x0];
#pragma unroll
        for (int i = 0; i < 3; i++) {
            float r[6];
#pragma unroll
            for (int k = 0; k < 6; k++) r[k] = base[i * 30 + k];
            if (i == 1) { ctr[0] = r[1]; ctr[1] = r[2]; ctr[2] = r[3]; ctr[3] = r[4]; }
#pragma unroll
            for (int j = 0; j < 3; j++)
#pragma unroll
                for (int q = 0; q < 4; q++)
                    acc[q] += w9[i * 3 + j] * r[j + q];
        }
        float v0 = ctr[0] + acc[0] * sc + bb;
        float v1 = ctr[1] + acc[1] * sc + bb;
        float v2 = ctr[2] + acc[2] * sc + bb;
        float v3 = ctr[3] + acc[3] * sc + bb;

        if (WF) {   // fp32 NCHW write (only when a consumer needs it)
            float4 o; o.x = v0; o.y = v1; o.z = v2; o.w = v3;
            *(float4*)&op[lm * PP + row * 28 + x0] = o;
        }

        // 4x4 transpose across the 4-lane group (static indices only)
        float ea = __shfl_xor((lm & 2) ? v0 : v2, 2);
        float eb = __shfl_xor((lm & 2) ? v1 : v3, 2);
        v0 = (lm & 2) ? ea : v0;  v1 = (lm & 2) ? eb : v1;
        v2 = (lm & 2) ? v2 : ea;  v3 = (lm & 2) ? v3 : eb;
        float ec = __shfl_xor((lm & 1) ? v0 : v1, 1);
        float ed = __shfl_xor((lm & 1) ? v2 : v3, 1);
        v0 = (lm & 1) ? ec : v0;  v1 = (lm & 1) ? v1 : ec;
        v2 = (lm & 1) ? ed : v2;  v3 = (lm & 1) ? v3 : ed;
        // lane q holds channels c0..c0+3 of pixel row*28 + x0 + q
        int p = row * 28 + x0 + lm;
        union { unsigned short h[4]; uint2 u; } pk;
        pk.h[0] = f2bits(v0); pk.h[1] = f2bits(v1);
        pk.h[2] = f2bits(v2); pk.h[3] = f2bits(v3);
        *(uint2*)&oBu[((size_t)n * PP + p) * DIMC + c0] = pk.u;
    }
}

// ---------------------------------------------------------------------------
// Per-head depthwise 5x5 + BN on q channels — round-5 LDS version (proven).
// grid (NHH, BB), block 256, LDS 32 KB.
// ---------------------------------------------------------------------------
__global__ __launch_bounds__(256) void dws5x5_nhwc(
    const bf16* __restrict__ qkv,   // [64][784][384]
    const float* __restrict__ w,    // [64][25]  (hk-major)
    const float* __restrict__ s, const float* __restrict__ b,
    bf16* __restrict__ qout)        // [64][784][64]
{
    __shared__ __align__(16) unsigned short qin[32 * 32 * 16];  // [r][c][ch]
    int hh  = blockIdx.x;
    int n   = blockIdx.y;
    int tid = threadIdx.x;
    const unsigned short* KVu = (const unsigned short*)qkv;

    int kcw = tid & 15;
    int hk  = hh * 16 + kcw;
    float w25[25];
#pragma unroll
    for (int i = 0; i < 25; i++) w25[i] = w[hk * 25 + i];
    float csc = s[hk], cbb = b[hk];

    // zero-fill (halo must be 0), then stage interior
    for (int i = tid; i < 4096; i += 256)
        ((uint4*)qin)[i] = make_uint4(0u, 0u, 0u, 0u);
    __syncthreads();
    for (int idx = tid; idx < 1568; idx += 256) {
        int p = idx >> 1, half = idx & 1;
        int h = p / 28, x = p - h * 28;
        uint4 v = *(const uint4*)&KVu[((size_t)n * PP + p) * 384 + hh * 96 + half * 8];
        *(uint4*)&qin[((h + 2) * 32 + (x + 2)) * 16 + half * 8] = v;
    }
    __syncthreads();

    // compute: 784 px x 16 ch tasks
    for (int idx = tid; idx < 12544; idx += 256) {
        int p = idx >> 4;            // channel == kcw since 256 % 16 == 0
        int h = p / 28, x = p - h * 28;
        float acc = 0.f;
#pragma unroll
        for (int i = 0; i < 5; i++)
#pragma unroll
            for (int j = 0; j < 5; j++)
                acc += w25[i * 5 + j] * bits2f(qin[((h + i) * 32 + (x + j)) * 16 + kcw]);
        qout[((size_t)n * PP + p) * 64 + hk] = __float2bfloat16(acc * csc + cbb);
    }
}

// ---------------------------------------------------------------------------
// 1x1 conv as bf16 MFMA GEMM — gll staging + XCD swizzle (proven) + round-13
// RESMODE 2 (residual from bf16 NHWC mirror; makes upstream fp32 writes dead).
// RESMODE: 0 none | 1 fp32 NCHW | 2 bf16 NHWC.
// OUTMODE: 0 bf16 NHWC | 1 fp32 NCHW | 2 both.       grid (7, M/64, 64)
// ---------------------------------------------------------------------------
template <bool RELU, int RESMODE, int OUTMODE>
__global__ __launch_bounds__(256) void gemm_mfma(
    const bf16* __restrict__ Wb,    // [M][K] bf16
    const bf16* __restrict__ X,     // [64][784][K] bf16 NHWC
    const float* __restrict__ S, const float* __restrict__ Bb,
    const float* __restrict__ resF, // [64][M][784] fp32 NCHW (RESMODE 1)
    const bf16*  __restrict__ resB, // [64][784][M] bf16 NHWC (RESMODE 2)
    float* __restrict__ outF,       // fp32 NCHW (OUTMODE 1/2)
    bf16*  __restrict__ outB,       // bf16 NHWC (OUTMODE 0/2)
    int M, int K)
{
    // chunked-XCD bijective remap (nwg % 8 == 0 for all instantiations)
    int nwg = gridDim.x * gridDim.y * gridDim.z;
    int wid = (blockIdx.z * gridDim.y + blockIdx.y) * gridDim.x + blockIdx.x;
    int lin = (wid & 7) * (nwg >> 3) + (wid >> 3);
    int yb  = lin % gridDim.y;             // co-tile (fastest: shares X panel)
    int t2  = lin / gridDim.y;
    int xb  = t2 % gridDim.x;              // p-tile
    int n   = t2 / gridDim.x;              // image

    int co0  = yb * 64;
    int p0   = xb * 112;
    int tid  = threadIdx.x;
    int wv   = tid >> 6;
    int ln   = tid & 63;
    int l15  = ln & 15;
    int quad = ln >> 4;

    __shared__ __align__(16) unsigned short Blds[2][112 * 32];  // linear 64B rows

    floatx4 acc[7];
#pragma unroll
    for (int t = 0; t < 7; t++) acc[t] = (floatx4){0.f, 0.f, 0.f, 0.f};

    const bf16* Arow = Wb + (size_t)(co0 + wv * 16 + l15) * K + quad * 8;
    const unsigned short* Xb = (const unsigned short*)X + ((size_t)n * PP + p0) * K;

    // staging geometry: issue A covers rows 0..63 (all waves), issue B rows
    // 64..111 (waves 0..2). dest = wave-uniform LDS base + lane*16.
    int rA = wv * 16 + (ln >> 2);            // 0..63
    int rB = 64 + wv * 16 + (ln >> 2);       // 64..111 (wv<3)
    int cA = (ln & 3) ^ ((rA >> 1) & 3);     // pre-swizzled source chunk
    int cB = (ln & 3) ^ ((rB >> 1) & 3);
    const unsigned short* gA = Xb + (size_t)rA * K + cA * 8;
    const unsigned short* gB = Xb + (size_t)rB * K + cB * 8;

    // prologue: stage tile 0
    gll16(gA, &Blds[0][(wv * 16) * 32]);
    if (wv < 3) gll16(gB, &Blds[0][(64 + wv * 16) * 32]);
    short8 af = *(const short8*)Arow;
    __syncthreads();

    int NT = K >> 5;
    for (int t = 0; t < NT; t++) {
        int cur = t & 1;
        short8 naf = af;
        if (t + 1 < NT) {
            gll16(gA + (t + 1) * 32, &Blds[cur ^ 1][(wv * 16) * 32]);
            if (wv < 3) gll16(gB + (t + 1) * 32, &Blds[cur ^ 1][(64 + wv * 16) * 32]);
            naf = *(const short8*)(Arow + (t + 1) * 32);
        }
#pragma unroll
        for (int tt = 0; tt < 7; tt++) {
            int row = tt * 16 + l15;
            short8 bfrag = *(const short8*)
                &Blds[cur][row * 32 + ((quad ^ ((row >> 1) & 3)) * 8)];
            acc[tt] = __builtin_amdgcn_mfma_f32_16x16x32_bf16(af, bfrag, acc[tt], 0, 0, 0);
        }
        af = naf;
        __syncthreads();   // vmcnt(0) drain (stage done) + reads of buf[cur] done
    }

    int cobase = co0 + wv * 16 + quad * 4;
    float s4[4], b4[4];
#pragma unroll
    for (int r = 0; r < 4; r++) { s4[r] = S[cobase + r]; b4[r] = Bb[cobase + r]; }

#pragma unroll
    for (int t = 0; t < 7; t++) {
        int p = p0 + t * 16 + l15;   // always < 784
        float resv[4] = {0.f, 0.f, 0.f, 0.f};
        if (RESMODE == 1) {
#pragma unroll
            for (int r = 0; r < 4; r++)
                resv[r] = resF[((size_t)n * M + cobase + r) * PP + p];
        }
        if (RESMODE == 2) {
            union { uint2 u; unsigned short h[4]; } rr;
            rr.u = *(const uint2*)((const unsigned short*)resB +
                                   ((size_t)n * PP + p) * M + cobase);
#pragma unroll
            for (int r = 0; r < 4; r++) resv[r] = bits2f(rr.h[r]);
        }
        float y[4];
#pragma unroll
        for (int r = 0; r < 4; r++) {
            y[r] = acc[t][r] * s4[r] + b4[r];
            if (RELU) y[r] = fmaxf(y[r], 0.f);
            if (RESMODE != 0) y[r] += resv[r];
        }
        if (OUTMODE == 1 || OUTMODE == 2) {
#pragma unroll
            for (int r = 0; r < 4; r++)
                outF[((size_t)n * M + cobase + r) * PP + p] = y[r];
        }
        if (OUTMODE == 0 || OUTMODE == 2) {
            union { unsigned short h4[4]; uint2 u; } pk;
#pragma unroll
            for (int r = 0; r < 4; r++) pk.h4[r] = f2bits(y[r]);
            *(uint2*)((unsigned short*)outB + ((size_t)n * PP + p) * M + cobase) = pk.u;
        }
    }
}

// ---------------------------------------------------------------------------
// 7x7 window attention — round-1 MFMA version (proven).
// grid (8, 4, 64), block 256.
// ---------------------------------------------------------------------------
__global__ __launch_bounds__(256) void attn_kernel(
    const bf16*  __restrict__ Q,       // [64][784][64] NHWC (hk = hh*16+kc)
    const bf16*  __restrict__ KV,      // [64][784][384] NHWC
    const float* __restrict__ pos,     // [4][49][49]
    bf16* __restrict__ O)              // [64][784][256] NHWC (c = hh*64+d)
{
    int wjp = blockIdx.x & 1, wi = blockIdx.x >> 1;
    int hh  = blockIdx.y, n = blockIdx.z;
    int tid = threadIdx.x;
    int pbase = wi * 7 * 28 + wjp * 14;

    __shared__ __align__(16) char smem[51712];
    unsigned short* qS = (unsigned short*)smem;              // [2][64][40]
    unsigned short* kS = qS + 2 * 64 * 40;                   // [2][64][40]
    unsigned short* pS = (unsigned short*)smem;              // alias: [2][64][72]
    unsigned short* vT = (unsigned short*)(smem + 20480);    // [2][64][72]
    float*          posL = (float*)(smem + 20480 + 18432);   // [64][50]

    const unsigned short* Qu  = (const unsigned short*)Q;
    const unsigned short* KVu = (const unsigned short*)KV;

    // ---- load q, k: 2 bufs x 2 windows x 64 rows x 5 halves (zero-padded) ----
    for (int idx = tid; idx < 1280; idx += 256) {
        int which = idx >= 640 ? 1 : 0;
        int t2 = idx - which * 640;
        int w = t2 / 320, rm = t2 - w * 320;
        int row = rm / 5, half = rm - row * 5;
        uint4 v = make_uint4(0u, 0u, 0u, 0u);
        if (row < 49 && half < 2) {
            int p = pbase + (row / 7) * 28 + w * 7 + (row % 7);
            const unsigned short* src = which
                ? &KVu[((size_t)n * PP + p) * 384 + hh * 96 + 16 + half * 8]
                : &Qu[((size_t)n * PP + p) * 64 + hh * 16 + half * 8];
            v = *(const uint4*)src;
        }
        *(uint4*)((which ? kS : qS) + (w * 64 + row) * 40 + half * 8) = v;
    }
    // ---- stage V transposed: vT[w][d][ki], zero cols for ki >= 49 ----
    for (int idx = tid; idx < 1024; idx += 256) {
        int w = idx >> 9, rm = idx & 511;
        int ki = rm >> 3, dq = rm & 7;
        union { uint4 q; unsigned short h[8]; } v;
        v.q = make_uint4(0u, 0u, 0u, 0u);
        if (ki < 49) {
            int p = pbase + (ki / 7) * 28 + w * 7 + (ki % 7);
            v.q = *(const uint4*)&KVu[((size_t)n * PP + p) * 384 + hh * 96 + 32 + dq * 8];
        }
#pragma unroll
        for (int j = 0; j < 8; j++)
            vT[(w * 64 + dq * 8 + j) * 72 + ki] = v.h[j];
    }
    // ---- stage pos [64][50], zero-padded ----
    for (int idx = tid; idx < 3200; idx += 256) {
        int r = idx / 50, c = idx - r * 50;
        posL[idx] = (r < 49 && c < 49) ? pos[((size_t)hh * 49 + r) * 49 + c] : 0.f;
    }
    __syncthreads();

    int wv = tid >> 6, ln = tid & 63, l15 = ln & 15, quad = ln >> 4;

    // ---- S^T via MFMA + in-register softmax; hold packed bf16 P ----
    uint2 pk[2][4];
#pragma unroll
    for (int w = 0; w < 2; w++) {
        short8 qf = *(const short8*)&qS[(w * 64 + wv * 16 + l15) * 40 + quad * 8];
        floatx4 a4[4];
#pragma unroll
        for (int kt = 0; kt < 4; kt++) {
            short8 kf = *(const short8*)&kS[(w * 64 + kt * 16 + l15) * 40 + quad * 8];
            a4[kt] = __builtin_amdgcn_mfma_f32_16x16x32_bf16(
                kf, qf, (floatx4){0.f, 0.f, 0.f, 0.f}, 0, 0, 0);
        }
        int q = wv * 16 + l15;
        float sv[16];
        float m = -1e30f;
#pragma unroll
        for (int kt = 0; kt < 4; kt++) {
#pragma unroll
            for (int r = 0; r < 4; r++) {
                int ki = kt * 16 + quad * 4 + r;
                float sc = (ki < 49)
                    ? a4[kt][r] * 0.25f + posL[q * 50 + ki]
                    : -1e30f;
                sv[kt * 4 + r] = sc;
                m = fmaxf(m, sc);
            }
        }
        m = fmaxf(m, __shfl_xor(m, 16));
        m = fmaxf(m, __shfl_xor(m, 32));
        float sum = 0.f;
#pragma unroll
        for (int i = 0; i < 16; i++) { sv[i] = __expf(sv[i] - m); sum += sv[i]; }
        sum += __shfl_xor(sum, 16);
        sum += __shfl_xor(sum, 32);
        float inv = 1.f / sum;
#pragma unroll
        for (int kt = 0; kt < 4; kt++) {
            union { uint2 u; unsigned short h[4]; } pku;
#pragma unroll
            for (int r = 0; r < 4; r++) pku.h[r] = f2bits(sv[kt * 4 + r] * inv);
            pk[w][kt] = pku.u;
        }
    }
    __syncthreads();   // all qS/kS MFMA reads done before aliasing writes

    {
        int q = wv * 16 + l15;
#pragma unroll
        for (int w = 0; w < 2; w++)
#pragma unroll
            for (int kt = 0; kt < 4; kt++)
                *(uint2*)&pS[(w * 64 + q) * 72 + kt * 16 + quad * 4] = pk[w][kt];
    }
    __syncthreads();

    // ---- O = relu(P @ V) via MFMA ----
    unsigned short* Ou = (unsigned short*)O;
#pragma unroll
    for (int w = 0; w < 2; w++) {
        short8 af0 = *(const short8*)&pS[(w * 64 + wv * 16 + l15) * 72 + quad * 8];
        short8 af1 = *(const short8*)&pS[(w * 64 + wv * 16 + l15) * 72 + 32 + quad * 8];
#pragma unroll
        for (int dt = 0; dt < 4; dt++) {
            floatx4 oacc = (floatx4){0.f, 0.f, 0.f, 0.f};
            short8 vf0 = *(const short8*)&vT[(w * 64 + dt * 16 + l15) * 72 + quad * 8];
            short8 vf1 = *(const short8*)&vT[(w * 64 + dt * 16 + l15) * 72 + 32 + quad * 8];
            oacc = __builtin_amdgcn_mfma_f32_16x16x32_bf16(af0, vf0, oacc, 0, 0, 0);
            oacc = __builtin_amdgcn_mfma_f32_16x16x32_bf16(af1, vf1, oacc, 0, 0, 0);
#pragma unroll
            for (int r = 0; r < 4; r++) {
                int q = wv * 16 + quad * 4 + r;
                if (q < 49) {
                    int p = pbase + (q / 7) * 28 + w * 7 + (q % 7);
                    Ou[((size_t)n * PP + p) * 256 + hh * 64 + dt * 16 + l15] =
                        f2bits(fmaxf(oacc[r], 0.f));
                }
            }
        }
    }
}

// ---------------------------------------------------------------------------
extern "C" void kernel_launch(void* const* d_in, const int* in_sizes, int n_in,
                              void* d_out, int out_size, void* d_ws, size_t ws_size,
                              hipStream_t stream)
{
    const float* x0     = (const float*)d_in[0];
    const float* dw0_w  = (const float*)d_in[1];
    const float* dw0_s  = (const float*)d_in[2];
    const float* dw0_b  = (const float*)d_in[3];
    const float* dw1_w  = (const float*)d_in[4];
    const float* dw1_s  = (const float*)d_in[5];
    const float* dw1_b  = (const float*)d_in[6];
    const float* f0w1   = (const float*)d_in[7];
    const float* f0s1   = (const float*)d_in[8];
    const float* f0b1   = (const float*)d_in[9];
    const float* f0w2   = (const float*)d_in[10];
    const float* f0s2   = (const float*)d_in[11];
    const float* f0b2   = (const float*)d_in[12];
    const float* f1w1   = (const float*)d_in[13];
    const float* f1s1   = (const float*)d_in[14];
    const float* f1b1   = (const float*)d_in[15];
    const float* f1w2   = (const float*)d_in[16];
    const float* f1s2   = (const float*)d_in[17];
    const float* f1b2   = (const float*)d_in[18];
    const float* qkv_w  = (const float*)d_in[19];
    const float* qkv_s  = (const float*)d_in[20];
    const float* qkv_b  = (const float*)d_in[21];
    const float* dws_w  = (const float*)d_in[22];
    const float* dws_s  = (const float*)d_in[23];
    const float* dws_b  = (const float*)d_in[24];
    const float* proj_w = (const float*)d_in[25];
    const float* proj_s = (const float*)d_in[26];
    const float* proj_b = (const float*)d_in[27];
    const float* pos    = (const float*)d_in[28];

    // -------- workspace (aliased) --------
    const size_t NXB = (size_t)BB * DIMC * PP * 4;    // 51,380,224 B
    char* base  = (char*)d_ws;
    float* X1   = (float*)base;
    bf16*  Hb   = (bf16*)(base + NXB);
    bf16*  Qb   = Hb;                                  // alias, disjoint in time
    char*  C_   = base + 2 * NXB;
    bf16*  QKVb = (bf16*)C_;
    bf16*  X1b  = (bf16*)(base + 3 * NXB);             // 25.7 MB
    bf16*  Wc   = (bf16*)(base + 3 * NXB + NXB / 2);
    bf16*  Ob   = (bf16*)d_out;
    float* outp = (float*)d_out;

    bf16* Wf0w1 = Wc;                  // [512][256]
    bf16* Wf0w2 = Wf0w1 + 131072;      // [256][512]
    bf16* Wf1w1 = Wf0w2 + 131072;      // [512][256]
    bf16* Wf1w2 = Wf1w1 + 131072;      // [256][512]
    bf16* Wqkv  = Wf1w2 + 131072;      // [384][256]
    bf16* Wproj = Wqkv + 98304;        // [256][256]

    dim3 blk(256);

    // 0) weights fp32 -> bf16 (single merged launch)
    cvt_all<<<2688, blk, 0, stream>>>(f0w1, Wf0w1, f0w2, Wf0w2,
                                      f1w1, Wf1w1, f1w2, Wf1w2,
                                      qkv_w, Wqkv, proj_w, Wproj);

    // 1) x = x + dw0(x) -> bf16 NHWC mirror only (fp32 write dead: the only
    //    consumer was ffn0-w2's residual, now RESMODE 2 from X1b)
    dw3x3_kernel<false><<<dim3(DIMC / CPB, BB), blk, 0, stream>>>(
        x0, dw0_w, dw0_s, dw0_b, X1, X1b);

    // 2-3) ffn0: w2 res from X1b (bf16), writes X1b in-place (bf16 only)
    gemm_mfma<true, 0, 0><<<dim3(7, HIDC / 64, BB), blk, 0, stream>>>(
        Wf0w1, X1b, f0s1, f0b1, nullptr, nullptr, nullptr, Hb, HIDC, DIMC);
    gemm_mfma<false, 2, 0><<<dim3(7, DIMC / 64, BB), blk, 0, stream>>>(
        Wf0w2, Hb, f0s2, f0b2, nullptr, X1b, nullptr, X1b, DIMC, HIDC);

    // 4-7) attention; proj res from X1b (post-ffn0), writes X1 fp32 (dw1 input)
    gemm_mfma<false, 0, 0><<<dim3(7, 384 / 64, BB), blk, 0, stream>>>(
        Wqkv, X1b, qkv_s, qkv_b, nullptr, nullptr, nullptr, QKVb, 384, DIMC);
    dws5x5_nhwc<<<dim3(NHH, BB), blk, 0, stream>>>(QKVb, dws_w, dws_s, dws_b, Qb);
    attn_kernel<<<dim3(8, NHH, BB), blk, 0, stream>>>(Qb, QKVb, pos, Ob);
    gemm_mfma<false, 2, 1><<<dim3(7, DIMC / 64, BB), blk, 0, stream>>>(
        Wproj, Ob, proj_s, proj_b, nullptr, X1b, X1, nullptr, DIMC, DIMC);

    // 8) x = x + dw1(x): bf16 NHWC mirror only (fp32 write dead: ffn1-w2's
    //    residual now reads X1b)
    dw3x3_kernel<false><<<dim3(DIMC / CPB, BB), blk, 0, stream>>>(
        X1, dw1_w, dw1_s, dw1_b, X1, X1b);

    // 9-10) ffn1: w2 res from X1b, final fp32 NCHW to d_out
    gemm_mfma<true, 0, 0><<<dim3(7, HIDC / 64, BB), blk, 0, stream>>>(
        Wf1w1, X1b, f1s1, f1b1, nullptr, nullptr, nullptr, Hb, HIDC, DIMC);
    gemm_mfma<false, 2, 1><<<dim3(7, DIMC / 64, BB), blk, 0, stream>>>(
        Wf1w2, Hb, f1s2, f1b2, nullptr, X1b, outp, nullptr, DIMC, HIDC);
}